// Round 3
// baseline (1786.009 us; speedup 1.0000x reference)
//
#include <hip/hip_runtime.h>
#include <hip/hip_bf16.h>

__device__ __forceinline__ float sigm(float x) {
  return 1.0f / (1.0f + __expf(-x));
}

// ---- hs accessors (f32 or bf16 storage) ----
__device__ __forceinline__ float ldh(const float* p, size_t i) { return p[i]; }
__device__ __forceinline__ float ldh(const __hip_bfloat16* p, size_t i) {
  return __bfloat162float(p[i]);
}
__device__ __forceinline__ void sth(float* p, size_t i, float v) { p[i] = v; }
__device__ __forceinline__ void sth(__hip_bfloat16* p, size_t i, float v) {
  p[i] = __float2bfloat16(v);
}

// ================= edge dtype autodetect =================
// int64 little-endian => every odd int32 word (high half) is zero.
__global__ void k_detect(const int* __restrict__ ei, int* __restrict__ flag) {
  if (threadIdx.x == 0 && blockIdx.x == 0) {
    int odd_nz = 0, even_nz = 0;
    for (int i = 0; i < 128; ++i) {
      odd_nz |= (ei[2 * i + 1] != 0);
      even_nz |= (ei[2 * i] != 0);
    }
    *flag = (even_nz && !odd_nz) ? 1 : 0;
  }
}

// ================= GCN =================

__global__ void k_count(const int* __restrict__ ei, int E,
                        const int* __restrict__ flag, int* __restrict__ cnt) {
  int e = blockIdx.x * blockDim.x + threadIdx.x;
  if (e < E) {
    int d = (*flag) ? ei[2 * (E + e)] : ei[E + e];
    atomicAdd(&cnt[d], 1);
  }
}

__global__ void k_dinv(const int* __restrict__ cnt, float* __restrict__ dinv, int N) {
  int i = blockIdx.x * blockDim.x + threadIdx.x;
  if (i < N) dinv[i] = rsqrtf((float)cnt[i] + 1.0f);  // +1 self-loop
}

// hs[n][g] = (x[n] @ W)[g] * dinv[n]
template <typename HT>
__global__ __launch_bounds__(256) void k_hs(const float* __restrict__ x,
                                            const float* __restrict__ Wg,
                                            const float* __restrict__ dinv,
                                            HT* __restrict__ hs, int N) {
  __shared__ __align__(16) float xt[64][132];
  __shared__ __align__(16) float Wl[128][32];
  int tid = threadIdx.x;
  int nb = blockIdx.x * 64;
  for (int i = tid; i < 4096; i += 256) Wl[i >> 5][i & 31] = Wg[i];
  const float4* xv = (const float4*)x;
  for (int i = tid; i < 2048; i += 256) {
    int r = i >> 5, c = i & 31;
    float4 v = make_float4(0.f, 0.f, 0.f, 0.f);
    if (nb + r < N) v = xv[(size_t)(nb + r) * 32 + c];
    *(float4*)&xt[r][c * 4] = v;
  }
  __syncthreads();
  int nl = tid >> 2, gq = (tid & 3) * 8;
  float a[8];
#pragma unroll
  for (int j = 0; j < 8; ++j) a[j] = 0.f;
  for (int k = 0; k < 128; ++k) {
    float xk = xt[nl][k];
#pragma unroll
    for (int j = 0; j < 8; ++j) a[j] += xk * Wl[k][gq + j];
  }
  int n = nb + nl;
  if (n < N) {
    float d = dinv[n];
#pragma unroll
    for (int j = 0; j < 8; ++j) sth(hs, (size_t)n * 32 + gq + j, a[j] * d);
  }
}

// per (edge, quarter-row): gout[dst] += hs[src]
template <typename HT>
__global__ void k_scatter(const int* __restrict__ ei, int E,
                          const int* __restrict__ flag,
                          const HT* __restrict__ hs, float* __restrict__ gout) {
  long long gid = (long long)blockIdx.x * blockDim.x + threadIdx.x;
  int e = (int)(gid >> 3), part = (int)(gid & 7);
  if (e >= E) return;
  int is64 = *flag;
  int s = is64 ? ei[2 * e] : ei[e];
  int d = is64 ? ei[2 * (E + e)] : ei[E + e];
  int b = part * 4;
  float* gp = gout + (size_t)d * 32 + b;
  size_t hp = (size_t)s * 32 + b;
  atomicAdd(gp + 0, ldh(hs, hp + 0));
  atomicAdd(gp + 1, ldh(hs, hp + 1));
  atomicAdd(gp + 2, ldh(hs, hp + 2));
  atomicAdd(gp + 3, ldh(hs, hp + 3));
}

// gout[n][g] = (scattered + hs[n][g]) * dinv[n] + bg[g]
template <typename HT>
__global__ void k_finish(const HT* __restrict__ hs, const float* __restrict__ dinv,
                         const float* __restrict__ bg, float* __restrict__ gout,
                         int N) {
  int gid = blockIdx.x * blockDim.x + threadIdx.x;
  if (gid < N * 32) {
    int n = gid >> 5, g = gid & 31;
    gout[gid] = (gout[gid] + ldh(hs, (size_t)gid)) * dinv[n] + bg[g];
  }
}

// ================= fp32 LSTM (unchanged control from round 2) =================
__global__ __launch_bounds__(256, 2) void k_lstm2(
    const float* __restrict__ gout,
    const float* __restrict__ wih0, const float* __restrict__ whh0,
    const float* __restrict__ bih0, const float* __restrict__ bhh0,
    const float* __restrict__ wih1, const float* __restrict__ whh1,
    const float* __restrict__ bih1, const float* __restrict__ bhh1,
    const float* __restrict__ fcw, const float* __restrict__ fcb,
    float* __restrict__ out, int N) {
  __shared__ __align__(16) float gbuf[4][32];
  __shared__ __align__(16) float h0b[4][52];
  __shared__ __align__(16) float h1b[4][52];
  __shared__ __align__(16) float pre[4][200];

  const int t = threadIdx.x;
  const int r = t;
  const int w = t >> 6;
  const int l = t & 63;
  const bool rowv = (r < 200);

  float wi0[32], wh0[52], wi1[52], wh1[52];
  float b0r = 0.f, b1r = 0.f;
#pragma unroll
  for (int k = 0; k < 32; ++k) wi0[k] = rowv ? wih0[r * 32 + k] : 0.f;
#pragma unroll
  for (int k = 0; k < 52; ++k) wh0[k] = (rowv && k < 50) ? whh0[r * 50 + k] : 0.f;
#pragma unroll
  for (int k = 0; k < 52; ++k) wi1[k] = (rowv && k < 50) ? wih1[r * 50 + k] : 0.f;
#pragma unroll
  for (int k = 0; k < 52; ++k) wh1[k] = (rowv && k < 50) ? whh1[r * 50 + k] : 0.f;
  if (rowv) { b0r = bih0[r] + bhh0[r]; b1r = bih1[r] + bhh1[r]; }
  const float fcw_l = (l < 50) ? fcw[l] : 0.f;
  const float fcb0 = fcb[0];

  for (int nb = blockIdx.x * 4; nb < N; nb += gridDim.x * 4) {
    for (int i = t; i < 4 * 52; i += 256) {
      h0b[i / 52][i % 52] = 0.f;
      h1b[i / 52][i % 52] = 0.f;
    }
    for (int i = t; i < 4 * 32; i += 256) {
      int p = i >> 5, k = i & 31;
      int node = nb + p;
      gbuf[p][k] = (node < N) ? gout[(size_t)node * 32 + k] : 0.f;
    }
    float c0 = 0.f, c1 = 0.f;
    __syncthreads();

    for (int s = 0; s < 10; ++s) {
      if (rowv) {
#pragma unroll
        for (int p = 0; p < 4; ++p) {
          float a0 = b0r, a1 = 0.f, a2 = 0.f, a3 = 0.f;
#pragma unroll
          for (int k = 0; k < 8; ++k) {
            float4 v = *(const float4*)&gbuf[p][4 * k];
            a0 += wi0[4*k+0] * v.x; a1 += wi0[4*k+1] * v.y;
            a2 += wi0[4*k+2] * v.z; a3 += wi0[4*k+3] * v.w;
          }
#pragma unroll
          for (int k = 0; k < 13; ++k) {
            float4 v = *(const float4*)&h0b[p][4 * k];
            a0 += wh0[4*k+0] * v.x; a1 += wh0[4*k+1] * v.y;
            a2 += wh0[4*k+2] * v.z; a3 += wh0[4*k+3] * v.w;
          }
          pre[p][r] = (a0 + a1) + (a2 + a3);
        }
      }
      __syncthreads();
      if (l < 50) {
        float iv = sigm(pre[w][l]);
        float fv = sigm(pre[w][50 + l]);
        float gv = tanhf(pre[w][100 + l]);
        float ov = sigm(pre[w][150 + l]);
        c0 = fv * c0 + iv * gv;
        h0b[w][l] = ov * tanhf(c0);
      }
      __syncthreads();
      if (rowv) {
#pragma unroll
        for (int p = 0; p < 4; ++p) {
          float a0 = b1r, a1 = 0.f, a2 = 0.f, a3 = 0.f;
#pragma unroll
          for (int k = 0; k < 13; ++k) {
            float4 v = *(const float4*)&h0b[p][4 * k];
            a0 += wi1[4*k+0] * v.x; a1 += wi1[4*k+1] * v.y;
            a2 += wi1[4*k+2] * v.z; a3 += wi1[4*k+3] * v.w;
          }
#pragma unroll
          for (int k = 0; k < 13; ++k) {
            float4 v = *(const float4*)&h1b[p][4 * k];
            a0 += wh1[4*k+0] * v.x; a1 += wh1[4*k+1] * v.y;
            a2 += wh1[4*k+2] * v.z; a3 += wh1[4*k+3] * v.w;
          }
          pre[p][r] = (a0 + a1) + (a2 + a3);
        }
      }
      __syncthreads();
      if (l < 50) {
        float iv = sigm(pre[w][l]);
        float fv = sigm(pre[w][50 + l]);
        float gv = tanhf(pre[w][100 + l]);
        float ov = sigm(pre[w][150 + l]);
        c1 = fv * c1 + iv * gv;
        h1b[w][l] = ov * tanhf(c1);
      }
      __syncthreads();
    }
    float facc = (l < 50) ? fcw_l * h1b[w][l] : 0.f;
    facc += __shfl_xor(facc, 1);
    facc += __shfl_xor(facc, 2);
    facc += __shfl_xor(facc, 4);
    facc += __shfl_xor(facc, 8);
    facc += __shfl_xor(facc, 16);
    facc += __shfl_xor(facc, 32);
    int node = nb + w;
    if (l == 0 && node < N) out[node] = facc + fcb0;
    __syncthreads();
  }
}

// ================= host launcher =================
extern "C" void kernel_launch(void* const* d_in, const int* in_sizes, int n_in,
                              void* d_out, int out_size, void* d_ws, size_t ws_size,
                              hipStream_t stream) {
  const float* x    = (const float*)d_in[0];
  const float* Wg   = (const float*)d_in[1];
  const float* bg   = (const float*)d_in[2];
  const float* wih0 = (const float*)d_in[3];
  const float* whh0 = (const float*)d_in[4];
  const float* bih0 = (const float*)d_in[5];
  const float* bhh0 = (const float*)d_in[6];
  const float* wih1 = (const float*)d_in[7];
  const float* whh1 = (const float*)d_in[8];
  const float* bih1 = (const float*)d_in[9];
  const float* bhh1 = (const float*)d_in[10];
  const float* fcw  = (const float*)d_in[11];
  const float* fcb  = (const float*)d_in[12];
  const int*   edge = (const int*)d_in[13];
  int N = in_sizes[0] / 128;
  int E = in_sizes[13] / 2;

  // ---- ws_size-adaptive layout ----
  char* ws = (char*)d_ws;
  size_t off = 0;
  auto take = [&](size_t b) {
    size_t o = off;
    off = (off + b + 255) & ~(size_t)255;
    return o;
  };
  int*   cnt  = (int*)(ws + take((size_t)N * 4));
  float* dinv = (float*)(ws + take((size_t)N * 4));
  int*   flag = (int*)(ws + take(256));
  float* gout = (float*)(ws + take((size_t)N * 32 * 4));
  size_t hs_off = off;
  bool f32hs = (hs_off + (size_t)N * 32 * 4) <= ws_size;
  void* hs = (void*)(ws + take(f32hs ? (size_t)N * 32 * 4 : (size_t)N * 32 * 2));

  hipMemsetAsync(cnt, 0, (size_t)N * 4, stream);
  hipMemsetAsync(gout, 0, (size_t)N * 32 * 4, stream);
  k_detect<<<1, 1, 0, stream>>>(edge, flag);
  k_count<<<(E + 255) / 256, 256, 0, stream>>>(edge, E, flag, cnt);
  k_dinv<<<(N + 255) / 256, 256, 0, stream>>>(cnt, dinv, N);
  int sc_blocks = (int)(((long long)E * 8 + 255) / 256);
  if (f32hs) {
    k_hs<float><<<(N + 63) / 64, 256, 0, stream>>>(x, Wg, dinv, (float*)hs, N);
    k_scatter<float><<<sc_blocks, 256, 0, stream>>>(edge, E, flag, (const float*)hs, gout);
    k_finish<float><<<(N * 32 + 255) / 256, 256, 0, stream>>>((const float*)hs, dinv, bg, gout, N);
  } else {
    k_hs<__hip_bfloat16><<<(N + 63) / 64, 256, 0, stream>>>(x, Wg, dinv, (__hip_bfloat16*)hs, N);
    k_scatter<__hip_bfloat16><<<sc_blocks, 256, 0, stream>>>(edge, E, flag, (const __hip_bfloat16*)hs, gout);
    k_finish<__hip_bfloat16><<<(N * 32 + 255) / 256, 256, 0, stream>>>((const __hip_bfloat16*)hs, dinv, bg, gout, N);
  }
  k_lstm2<<<512, 256, 0, stream>>>(gout, wih0, whh0, bih0, bhh0,
                                   wih1, whh1, bih1, bhh1, fcw, fcb,
                                   (float*)d_out, N);
}

// Round 4
// 973.522 us; speedup vs baseline: 1.8346x; 1.8346x over previous
//
#include <hip/hip_runtime.h>
#include <hip/hip_bf16.h>

typedef __attribute__((ext_vector_type(8))) short short8;
typedef __attribute__((ext_vector_type(4))) float f32x4;

__device__ __forceinline__ float sigm(float x) {
  return 1.0f / (1.0f + __expf(-x));
}
__device__ __forceinline__ float tanh_(float x) {
  float xc = fminf(fmaxf(x, -15.0f), 15.0f);
  float e = __expf(2.0f * xc);
  return (e - 1.0f) / (e + 1.0f);
}
__device__ __forceinline__ short f2bf(float f) {
  union { __hip_bfloat16 b; short s; } u;
  u.b = __float2bfloat16(f);
  return u.s;
}

// ---- hs accessors (f32 or bf16 storage) ----
__device__ __forceinline__ float ldh(const float* p, size_t i) { return p[i]; }
__device__ __forceinline__ float ldh(const __hip_bfloat16* p, size_t i) {
  return __bfloat162float(p[i]);
}
__device__ __forceinline__ void sth(float* p, size_t i, float v) { p[i] = v; }
__device__ __forceinline__ void sth(__hip_bfloat16* p, size_t i, float v) {
  p[i] = __float2bfloat16(v);
}

// ---------------- weight image layout (bytes) ----------------
#define OFF_WIH0 0        // bf16 [208][32], swz (row&3)<<3
#define OFF_WHH0 13312    // bf16 [208][64], swz (row&7)<<3
#define OFF_WIH1 39936
#define OFF_WHH1 66560
#define OFF_B0   93184    // f32 [208]
#define OFF_B1   94016
#define OFF_FCW  94848    // f32 [52]
#define IMG_BYTES 95056   // = 5941 * 16

// ================= edge dtype autodetect =================
__global__ void k_detect(const int* __restrict__ ei, int* __restrict__ flag) {
  if (threadIdx.x == 0 && blockIdx.x == 0) {
    int odd_nz = 0, even_nz = 0;
    for (int i = 0; i < 128; ++i) {
      odd_nz |= (ei[2 * i + 1] != 0);
      even_nz |= (ei[2 * i] != 0);
    }
    *flag = (even_nz && !odd_nz) ? 1 : 0;
  }
}

// ================= GCN (proven round-3 path, unchanged) =================

__global__ void k_count(const int* __restrict__ ei, int E,
                        const int* __restrict__ flag, int* __restrict__ cnt) {
  int e = blockIdx.x * blockDim.x + threadIdx.x;
  if (e < E) {
    int d = (*flag) ? ei[2 * (E + e)] : ei[E + e];
    atomicAdd(&cnt[d], 1);
  }
}

__global__ void k_dinv(const int* __restrict__ cnt, float* __restrict__ dinv, int N) {
  int i = blockIdx.x * blockDim.x + threadIdx.x;
  if (i < N) dinv[i] = rsqrtf((float)cnt[i] + 1.0f);  // +1 self-loop
}

template <typename HT>
__global__ __launch_bounds__(256) void k_hs(const float* __restrict__ x,
                                            const float* __restrict__ Wg,
                                            const float* __restrict__ dinv,
                                            HT* __restrict__ hs, int N) {
  __shared__ __align__(16) float xt[64][132];
  __shared__ __align__(16) float Wl[128][32];
  int tid = threadIdx.x;
  int nb = blockIdx.x * 64;
  for (int i = tid; i < 4096; i += 256) Wl[i >> 5][i & 31] = Wg[i];
  const float4* xv = (const float4*)x;
  for (int i = tid; i < 2048; i += 256) {
    int r = i >> 5, c = i & 31;
    float4 v = make_float4(0.f, 0.f, 0.f, 0.f);
    if (nb + r < N) v = xv[(size_t)(nb + r) * 32 + c];
    *(float4*)&xt[r][c * 4] = v;
  }
  __syncthreads();
  int nl = tid >> 2, gq = (tid & 3) * 8;
  float a[8];
#pragma unroll
  for (int j = 0; j < 8; ++j) a[j] = 0.f;
  for (int k = 0; k < 128; ++k) {
    float xk = xt[nl][k];
#pragma unroll
    for (int j = 0; j < 8; ++j) a[j] += xk * Wl[k][gq + j];
  }
  int n = nb + nl;
  if (n < N) {
    float d = dinv[n];
#pragma unroll
    for (int j = 0; j < 8; ++j) sth(hs, (size_t)n * 32 + gq + j, a[j] * d);
  }
}

template <typename HT>
__global__ void k_scatter(const int* __restrict__ ei, int E,
                          const int* __restrict__ flag,
                          const HT* __restrict__ hs, float* __restrict__ gout) {
  long long gid = (long long)blockIdx.x * blockDim.x + threadIdx.x;
  int e = (int)(gid >> 3), part = (int)(gid & 7);
  if (e >= E) return;
  int is64 = *flag;
  int s = is64 ? ei[2 * e] : ei[e];
  int d = is64 ? ei[2 * (E + e)] : ei[E + e];
  int b = part * 4;
  float* gp = gout + (size_t)d * 32 + b;
  size_t hp = (size_t)s * 32 + b;
  atomicAdd(gp + 0, ldh(hs, hp + 0));
  atomicAdd(gp + 1, ldh(hs, hp + 1));
  atomicAdd(gp + 2, ldh(hs, hp + 2));
  atomicAdd(gp + 3, ldh(hs, hp + 3));
}

template <typename HT>
__global__ void k_finish(const HT* __restrict__ hs, const float* __restrict__ dinv,
                         const float* __restrict__ bg, float* __restrict__ gout,
                         int N) {
  int gid = blockIdx.x * blockDim.x + threadIdx.x;
  if (gid < N * 32) {
    int n = gid >> 5, g = gid & 31;
    gout[gid] = (gout[gid] + ldh(hs, (size_t)gid)) * dinv[n] + bg[g];
  }
}

// ================= weight image prep =================
// perm row = 4u+q holds source gate row q*50+u (i,f,g,o interleaved per unit)
__global__ void k_prep(const float* __restrict__ wih0, const float* __restrict__ whh0,
                       const float* __restrict__ wih1, const float* __restrict__ whh1,
                       const float* __restrict__ bih0, const float* __restrict__ bhh0,
                       const float* __restrict__ bih1, const float* __restrict__ bhh1,
                       const float* __restrict__ fcw, unsigned char* __restrict__ img) {
  int gid = blockIdx.x * blockDim.x + threadIdx.x;
  int nthr = gridDim.x * blockDim.x;
  {
    short* W = (short*)(img + OFF_WIH0);
    for (int i = gid; i < 208 * 32; i += nthr) {
      int row = i >> 5, k = i & 31, u = row >> 2, q = row & 3;
      float v = (u < 50) ? wih0[(q * 50 + u) * 32 + k] : 0.0f;
      W[row * 32 + (k ^ ((row & 3) << 3))] = f2bf(v);
    }
  }
  {
    short* W = (short*)(img + OFF_WHH0);
    for (int i = gid; i < 208 * 64; i += nthr) {
      int row = i >> 6, k = i & 63, u = row >> 2, q = row & 3;
      float v = (u < 50 && k < 50) ? whh0[(q * 50 + u) * 50 + k] : 0.0f;
      W[row * 64 + (k ^ ((row & 7) << 3))] = f2bf(v);
    }
  }
  {
    short* W = (short*)(img + OFF_WIH1);
    for (int i = gid; i < 208 * 64; i += nthr) {
      int row = i >> 6, k = i & 63, u = row >> 2, q = row & 3;
      float v = (u < 50 && k < 50) ? wih1[(q * 50 + u) * 50 + k] : 0.0f;
      W[row * 64 + (k ^ ((row & 7) << 3))] = f2bf(v);
    }
  }
  {
    short* W = (short*)(img + OFF_WHH1);
    for (int i = gid; i < 208 * 64; i += nthr) {
      int row = i >> 6, k = i & 63, u = row >> 2, q = row & 3;
      float v = (u < 50 && k < 50) ? whh1[(q * 50 + u) * 50 + k] : 0.0f;
      W[row * 64 + (k ^ ((row & 7) << 3))] = f2bf(v);
    }
  }
  {
    float* B = (float*)(img + OFF_B0);
    for (int i = gid; i < 208; i += nthr) {
      int u = i >> 2, q = i & 3;
      B[i] = (u < 50) ? bih0[q * 50 + u] + bhh0[q * 50 + u] : 0.0f;
    }
  }
  {
    float* B = (float*)(img + OFF_B1);
    for (int i = gid; i < 208; i += nthr) {
      int u = i >> 2, q = i & 3;
      B[i] = (u < 50) ? bih1[q * 50 + u] + bhh1[q * 50 + u] : 0.0f;
    }
  }
  {
    float* F = (float*)(img + OFF_FCW);
    for (int i = gid; i < 52; i += nthr) F[i] = (i < 50) ? fcw[i] : 0.0f;
  }
}

// ================= fused 2-layer MFMA LSTM over 10 steps + FC =================
// block = 512 thr (8 waves), wave owns 32 nodes (2 N-tiles of 16).
// gates^T = Wperm @ h^T via mfma_f32_16x16x32_bf16:
//   A lane: row=l&15, k=(l>>4)*8+j ; B lane: col(node)=l&15, k=(l>>4)*8+j
//   D lane: col(node)=l&15, row=(l>>4)*4+reg -> reg q = gate q of unit u=4t+(l>>4)
__global__ __launch_bounds__(512, 2) void k_lstm(const float* __restrict__ gout,
    const unsigned char* __restrict__ img, const float* __restrict__ fcb_p,
    float* __restrict__ out, int N) {
  __shared__ __align__(16) unsigned char smem[160592];  // 95056 img + 8*8192 staging
  const int tid = threadIdx.x;
  {  // copy weight image
    const uint4* s = (const uint4*)img;
    uint4* d = (uint4*)smem;
    for (int i = tid; i < IMG_BYTES / 16; i += 512) d[i] = s[i];
  }
  __syncthreads();
  const int lane = tid & 63, wid = tid >> 6;
  const int l15 = lane & 15, l4 = lane >> 4;
  const int swz7 = (l15 & 7) << 3, swz3 = (l15 & 3) << 3;
  const int node0 = blockIdx.x * 256 + wid * 32;

  const short* WIH0 = (const short*)(smem + OFF_WIH0);
  const short* WHH0 = (const short*)(smem + OFF_WHH0);
  const short* WIH1 = (const short*)(smem + OFF_WIH1);
  const short* WHH1 = (const short*)(smem + OFF_WHH1);
  const float* B0   = (const float*)(smem + OFF_B0);
  const float* B1   = (const float*)(smem + OFF_B1);
  const float* FCW  = (const float*)(smem + OFF_FCW);
  short* h0st = (short*)(smem + IMG_BYTES + wid * 8192);  // [32][64] bf16, swizzled
  short* h1st = h0st + 2048;

  {  // zero both staging buffers (8192 B)
    uint4 z; z.x = z.y = z.z = z.w = 0u;
    uint4* p = (uint4*)h0st;
    for (int i = lane; i < 512; i += 64) p[i] = z;
  }

  // gnn input fragments (B operand, K=32), kept in regs for all steps
  short8 gfrag[2];
#pragma unroll
  for (int v = 0; v < 2; ++v) {
    int node = node0 + v * 16 + l15;
    float4 a = make_float4(0.f,0.f,0.f,0.f), b = make_float4(0.f,0.f,0.f,0.f);
    if (node < N) {
      const float4* gp = (const float4*)(gout + (size_t)node * 32 + l4 * 8);
      a = gp[0]; b = gp[1];
    }
    short8 t;
    t[0]=f2bf(a.x); t[1]=f2bf(a.y); t[2]=f2bf(a.z); t[3]=f2bf(a.w);
    t[4]=f2bf(b.x); t[5]=f2bf(b.y); t[6]=f2bf(b.z); t[7]=f2bf(b.w);
    gfrag[v] = t;
  }

  float c0[13][2], c1[13][2];
#pragma unroll
  for (int t = 0; t < 13; ++t) { c0[t][0]=0.f; c0[t][1]=0.f; c1[t][0]=0.f; c1[t][1]=0.f; }
  float facc[2] = {0.f, 0.f};

#pragma unroll 1
  for (int s = 0; s < 10; ++s) {
    // load h-state B-fragments (old state; zeros at s=0)
    short8 h0f[2][2], h1f[2][2];
#pragma unroll
    for (int c = 0; c < 2; ++c)
#pragma unroll
      for (int v = 0; v < 2; ++v) {
        int nl = v * 16 + l15;
        h0f[c][v] = *(const short8*)(h0st + nl * 64 + ((c * 32 + l4 * 8) ^ swz7));
        h1f[c][v] = *(const short8*)(h1st + nl * 64 + ((c * 32 + l4 * 8) ^ swz7));
      }
    // ---- layer 0 ----
#pragma unroll
    for (int t = 0; t < 13; ++t) {
      f32x4 bv = *(const f32x4*)(B0 + t * 16 + l4 * 4);
      int arow = (16 * t + l15);
      short8 aih = *(const short8*)(WIH0 + arow * 32 + ((l4 * 8) ^ swz3));
      short8 ah0 = *(const short8*)(WHH0 + arow * 64 + ((l4 * 8) ^ swz7));
      short8 ah1 = *(const short8*)(WHH0 + arow * 64 + ((32 + l4 * 8) ^ swz7));
#pragma unroll
      for (int v = 0; v < 2; ++v) {
        f32x4 acc = bv;
        acc = __builtin_amdgcn_mfma_f32_16x16x32_bf16(aih, gfrag[v], acc, 0, 0, 0);
        acc = __builtin_amdgcn_mfma_f32_16x16x32_bf16(ah0, h0f[0][v], acc, 0, 0, 0);
        acc = __builtin_amdgcn_mfma_f32_16x16x32_bf16(ah1, h0f[1][v], acc, 0, 0, 0);
        float iv = sigm(acc[0]), fv = sigm(acc[1]);
        float gv = tanh_(acc[2]), ov = sigm(acc[3]);
        float c = fv * c0[t][v] + iv * gv;
        c0[t][v] = c;
        float h = ov * tanh_(c);
        h0st[(v * 16 + l15) * 64 + ((4 * t + l4) ^ swz7)] = f2bf(h);
      }
    }
    // re-read new h0 as B-fragments
    short8 h0nf[2][2];
#pragma unroll
    for (int c = 0; c < 2; ++c)
#pragma unroll
      for (int v = 0; v < 2; ++v) {
        int nl = v * 16 + l15;
        h0nf[c][v] = *(const short8*)(h0st + nl * 64 + ((c * 32 + l4 * 8) ^ swz7));
      }
    // ---- layer 1 ----
#pragma unroll
    for (int t = 0; t < 13; ++t) {
      f32x4 bv = *(const f32x4*)(B1 + t * 16 + l4 * 4);
      int arow = (16 * t + l15);
      short8 ai0 = *(const short8*)(WIH1 + arow * 64 + ((l4 * 8) ^ swz7));
      short8 ai1 = *(const short8*)(WIH1 + arow * 64 + ((32 + l4 * 8) ^ swz7));
      short8 ah0 = *(const short8*)(WHH1 + arow * 64 + ((l4 * 8) ^ swz7));
      short8 ah1 = *(const short8*)(WHH1 + arow * 64 + ((32 + l4 * 8) ^ swz7));
#pragma unroll
      for (int v = 0; v < 2; ++v) {
        f32x4 acc = bv;
        acc = __builtin_amdgcn_mfma_f32_16x16x32_bf16(ai0, h0nf[0][v], acc, 0, 0, 0);
        acc = __builtin_amdgcn_mfma_f32_16x16x32_bf16(ai1, h0nf[1][v], acc, 0, 0, 0);
        acc = __builtin_amdgcn_mfma_f32_16x16x32_bf16(ah0, h1f[0][v], acc, 0, 0, 0);
        acc = __builtin_amdgcn_mfma_f32_16x16x32_bf16(ah1, h1f[1][v], acc, 0, 0, 0);
        float iv = sigm(acc[0]), fv = sigm(acc[1]);
        float gv = tanh_(acc[2]), ov = sigm(acc[3]);
        float c = fv * c1[t][v] + iv * gv;
        c1[t][v] = c;
        float h = ov * tanh_(c);
        h1st[(v * 16 + l15) * 64 + ((4 * t + l4) ^ swz7)] = f2bf(h);
        if (s == 9) {
          int u = 4 * t + l4;
          facc[v] += FCW[u] * h;
        }
      }
    }
  }
  // FC epilogue: reduce over the 4 row-groups (lanes l, l^16, l^32, l^48)
  float fcb = fcb_p[0];
#pragma unroll
  for (int v = 0; v < 2; ++v) {
    float r = facc[v];
    r += __shfl_xor(r, 16);
    r += __shfl_xor(r, 32);
    int node = node0 + v * 16 + l15;
    if (l4 == 0 && node < N) out[node] = r + fcb;
  }
}

// ================= host launcher =================
extern "C" void kernel_launch(void* const* d_in, const int* in_sizes, int n_in,
                              void* d_out, int out_size, void* d_ws, size_t ws_size,
                              hipStream_t stream) {
  const float* x    = (const float*)d_in[0];
  const float* Wg   = (const float*)d_in[1];
  const float* bg   = (const float*)d_in[2];
  const float* wih0 = (const float*)d_in[3];
  const float* whh0 = (const float*)d_in[4];
  const float* bih0 = (const float*)d_in[5];
  const float* bhh0 = (const float*)d_in[6];
  const float* wih1 = (const float*)d_in[7];
  const float* whh1 = (const float*)d_in[8];
  const float* bih1 = (const float*)d_in[9];
  const float* bhh1 = (const float*)d_in[10];
  const float* fcw  = (const float*)d_in[11];
  const float* fcb  = (const float*)d_in[12];
  const int*   edge = (const int*)d_in[13];
  int N = in_sizes[0] / 128;
  int E = in_sizes[13] / 2;

  // ---- ws_size-adaptive layout ----
  char* ws = (char*)d_ws;
  size_t off = 0;
  auto take = [&](size_t b) {
    size_t o = off;
    off = (off + b + 255) & ~(size_t)255;
    return o;
  };
  int*   cnt  = (int*)(ws + take((size_t)N * 4));
  float* dinv = (float*)(ws + take((size_t)N * 4));
  int*   flag = (int*)(ws + take(256));
  unsigned char* wimg = (unsigned char*)(ws + take(IMG_BYTES));
  float* gout = (float*)(ws + take((size_t)N * 32 * 4));
  size_t hs_off = off;
  bool f32hs = (hs_off + (size_t)N * 32 * 4) <= ws_size;
  void* hs = (void*)(ws + take(f32hs ? (size_t)N * 32 * 4 : (size_t)N * 32 * 2));

  hipMemsetAsync(cnt, 0, (size_t)N * 4, stream);
  hipMemsetAsync(gout, 0, (size_t)N * 32 * 4, stream);
  k_detect<<<1, 1, 0, stream>>>(edge, flag);
  k_count<<<(E + 255) / 256, 256, 0, stream>>>(edge, E, flag, cnt);
  k_dinv<<<(N + 255) / 256, 256, 0, stream>>>(cnt, dinv, N);
  k_prep<<<52, 256, 0, stream>>>(wih0, whh0, wih1, whh1, bih0, bhh0, bih1, bhh1,
                                 fcw, wimg);
  int sc_blocks = (int)(((long long)E * 8 + 255) / 256);
  if (f32hs) {
    k_hs<float><<<(N + 63) / 64, 256, 0, stream>>>(x, Wg, dinv, (float*)hs, N);
    k_scatter<float><<<sc_blocks, 256, 0, stream>>>(edge, E, flag, (const float*)hs, gout);
    k_finish<float><<<(N * 32 + 255) / 256, 256, 0, stream>>>((const float*)hs, dinv, bg, gout, N);
  } else {
    k_hs<__hip_bfloat16><<<(N + 63) / 64, 256, 0, stream>>>(x, Wg, dinv, (__hip_bfloat16*)hs, N);
    k_scatter<__hip_bfloat16><<<sc_blocks, 256, 0, stream>>>(edge, E, flag, (const __hip_bfloat16*)hs, gout);
    k_finish<__hip_bfloat16><<<(N * 32 + 255) / 256, 256, 0, stream>>>((const __hip_bfloat16*)hs, dinv, bg, gout, N);
  }
  k_lstm<<<(N + 255) / 256, 512, 0, stream>>>(gout, wimg, fcb, (float*)d_out, N);
}

// Round 5
// 578.980 us; speedup vs baseline: 3.0848x; 1.6814x over previous
//
#include <hip/hip_runtime.h>
#include <hip/hip_bf16.h>

typedef __attribute__((ext_vector_type(8))) short short8;
typedef __attribute__((ext_vector_type(4))) float f32x4;

__device__ __forceinline__ float sigm(float x) {
  return 1.0f / (1.0f + __expf(-x));
}
__device__ __forceinline__ float tanh_(float x) {
  float xc = fminf(fmaxf(x, -15.0f), 15.0f);
  float e = __expf(2.0f * xc);
  return (e - 1.0f) / (e + 1.0f);
}
__device__ __forceinline__ short f2bf(float f) {
  union { __hip_bfloat16 b; short s; } u;
  u.b = __float2bfloat16(f);
  return u.s;
}

// ---- f32/bf16 storage accessors ----
__device__ __forceinline__ float ldh(const float* p, size_t i) { return p[i]; }
__device__ __forceinline__ float ldh(const __hip_bfloat16* p, size_t i) {
  return __bfloat162float(p[i]);
}
__device__ __forceinline__ void sth(float* p, size_t i, float v) { p[i] = v; }
__device__ __forceinline__ void sth(__hip_bfloat16* p, size_t i, float v) {
  p[i] = __float2bfloat16(v);
}

// gfrag loaders (8 consecutive elems at 16B-aligned base -> short8 of bf16)
__device__ __forceinline__ short8 load_gfrag(const float* g, size_t base) {
  const float4* gp = (const float4*)(g + base);
  float4 a = gp[0], b = gp[1];
  short8 t;
  t[0]=f2bf(a.x); t[1]=f2bf(a.y); t[2]=f2bf(a.z); t[3]=f2bf(a.w);
  t[4]=f2bf(b.x); t[5]=f2bf(b.y); t[6]=f2bf(b.z); t[7]=f2bf(b.w);
  return t;
}
__device__ __forceinline__ short8 load_gfrag(const __hip_bfloat16* g, size_t base) {
  return *(const short8*)(g + base);
}

// ---------------- weight image layout (bytes) ----------------
#define OFF_WIH0 0        // bf16 [208][32], swz (row&3)<<3
#define OFF_WHH0 13312    // bf16 [208][64], swz (row&7)<<3
#define OFF_WIH1 39936
#define OFF_WHH1 66560
#define OFF_B0   93184    // f32 [208]
#define OFF_B1   94016
#define OFF_FCW  94848    // f32 [52]
#define IMG_BYTES 95056   // = 5941 * 16

// ================= edge dtype autodetect =================
__global__ void k_detect(const int* __restrict__ ei, int* __restrict__ flag) {
  if (threadIdx.x == 0 && blockIdx.x == 0) {
    int odd_nz = 0, even_nz = 0;
    for (int i = 0; i < 128; ++i) {
      odd_nz |= (ei[2 * i + 1] != 0);
      even_nz |= (ei[2 * i] != 0);
    }
    *flag = (even_nz && !odd_nz) ? 1 : 0;
  }
}

// ================= GCN =================

__global__ void k_count(const int* __restrict__ ei, int E,
                        const int* __restrict__ flag, int* __restrict__ cnt) {
  int e = blockIdx.x * blockDim.x + threadIdx.x;
  if (e < E) {
    int d = (*flag) ? ei[2 * (E + e)] : ei[E + e];
    atomicAdd(&cnt[d], 1);
  }
}

__global__ void k_dinv(const int* __restrict__ cnt, float* __restrict__ dinv, int N) {
  int i = blockIdx.x * blockDim.x + threadIdx.x;
  if (i < N) dinv[i] = rsqrtf((float)cnt[i] + 1.0f);  // +1 self-loop
}

// in-place exclusive prefix sum over cnt[0..N): cnt becomes rowst (excl)
__global__ __launch_bounds__(1024) void k_scan(int* __restrict__ a, int N) {
  __shared__ int part[1024];
  int t = threadIdx.x;
  int chunk = (N + 1023) >> 10;
  int lo = t * chunk, hi = min(lo + chunk, N);
  int ssum = 0;
  for (int i = lo; i < hi; ++i) ssum += a[i];
  part[t] = ssum;
  __syncthreads();
  for (int off = 1; off < 1024; off <<= 1) {
    int v = (t >= off) ? part[t - off] : 0;
    __syncthreads();
    part[t] += v;
    __syncthreads();
  }
  int base = part[t] - ssum;  // exclusive prefix of this chunk
  for (int i = lo; i < hi; ++i) {
    int c = a[i];
    a[i] = base;
    base += c;
  }
}

// fill CSR; afterwards rowst[d] == end of segment d (start = rowst[d-1])
template <typename CT>
__global__ void k_fill(const int* __restrict__ ei, int E,
                       const int* __restrict__ flag,
                       int* __restrict__ rowst, CT* __restrict__ csr) {
  int e = blockIdx.x * blockDim.x + threadIdx.x;
  if (e < E) {
    int is64 = *flag;
    int s = is64 ? ei[2 * e] : ei[e];
    int d = is64 ? ei[2 * (E + e)] : ei[E + e];
    int p = atomicAdd(&rowst[d], 1);
    csr[p] = (CT)s;
  }
}

// hs[n][g] = (x[n] @ W)[g] * dinv[n]
template <typename HT>
__global__ __launch_bounds__(256) void k_hs(const float* __restrict__ x,
                                            const float* __restrict__ Wg,
                                            const float* __restrict__ dinv,
                                            HT* __restrict__ hs, int N) {
  __shared__ __align__(16) float xt[64][132];
  __shared__ __align__(16) float Wl[128][32];
  int tid = threadIdx.x;
  int nb = blockIdx.x * 64;
  for (int i = tid; i < 4096; i += 256) Wl[i >> 5][i & 31] = Wg[i];
  const float4* xv = (const float4*)x;
  for (int i = tid; i < 2048; i += 256) {
    int r = i >> 5, c = i & 31;
    float4 v = make_float4(0.f, 0.f, 0.f, 0.f);
    if (nb + r < N) v = xv[(size_t)(nb + r) * 32 + c];
    *(float4*)&xt[r][c * 4] = v;
  }
  __syncthreads();
  int nl = tid >> 2, gq = (tid & 3) * 8;
  float a[8];
#pragma unroll
  for (int j = 0; j < 8; ++j) a[j] = 0.f;
  for (int k = 0; k < 128; ++k) {
    float xk = xt[nl][k];
#pragma unroll
    for (int j = 0; j < 8; ++j) a[j] += xk * Wl[k][gq + j];
  }
  int n = nb + nl;
  if (n < N) {
    float d = dinv[n];
#pragma unroll
    for (int j = 0; j < 8; ++j) sth(hs, (size_t)n * 32 + gq + j, a[j] * d);
  }
}

// one wave per node: gout[n][g] = (sum_{j->n} hs[j][g] + hs[n][g])*dinv[n]+bg[g]
template <typename HT, typename GT, typename CT>
__global__ void k_gather(const CT* __restrict__ csr, const int* __restrict__ rowst,
                         const HT* __restrict__ hs, const float* __restrict__ dinv,
                         const float* __restrict__ bg, GT* __restrict__ gout,
                         int N) {
  int w = (blockIdx.x * blockDim.x + threadIdx.x) >> 6;
  if (w >= N) return;
  int lane = threadIdx.x & 63;
  int g = lane & 31, j = lane >> 5;
  int end = rowst[w];
  int start = (w == 0) ? 0 : rowst[w - 1];
  float acc = 0.0f;
  for (int k = start + j; k < end; k += 2)
    acc += ldh(hs, (size_t)csr[k] * 32 + g);
  acc += __shfl_xor(acc, 32);
  if (j == 0) {
    float v = (acc + ldh(hs, (size_t)w * 32 + g)) * dinv[w] + bg[g];
    sth(gout, (size_t)w * 32 + g, v);
  }
}

// ---- scatter fallback (only if ws too small for CSR) ----
template <typename HT>
__global__ void k_scatter(const int* __restrict__ ei, int E,
                          const int* __restrict__ flag,
                          const HT* __restrict__ hs, float* __restrict__ gout) {
  long long gid = (long long)blockIdx.x * blockDim.x + threadIdx.x;
  int e = (int)(gid >> 3), part = (int)(gid & 7);
  if (e >= E) return;
  int is64 = *flag;
  int s = is64 ? ei[2 * e] : ei[e];
  int d = is64 ? ei[2 * (E + e)] : ei[E + e];
  int b = part * 4;
  float* gp = gout + (size_t)d * 32 + b;
  size_t hp = (size_t)s * 32 + b;
  atomicAdd(gp + 0, ldh(hs, hp + 0));
  atomicAdd(gp + 1, ldh(hs, hp + 1));
  atomicAdd(gp + 2, ldh(hs, hp + 2));
  atomicAdd(gp + 3, ldh(hs, hp + 3));
}
template <typename HT>
__global__ void k_finish(const HT* __restrict__ hs, const float* __restrict__ dinv,
                         const float* __restrict__ bg, float* __restrict__ gout,
                         int N) {
  int gid = blockIdx.x * blockDim.x + threadIdx.x;
  if (gid < N * 32) {
    int n = gid >> 5, g = gid & 31;
    gout[gid] = (gout[gid] + ldh(hs, (size_t)gid)) * dinv[n] + bg[g];
  }
}

// ================= weight image prep =================
__global__ void k_prep(const float* __restrict__ wih0, const float* __restrict__ whh0,
                       const float* __restrict__ wih1, const float* __restrict__ whh1,
                       const float* __restrict__ bih0, const float* __restrict__ bhh0,
                       const float* __restrict__ bih1, const float* __restrict__ bhh1,
                       const float* __restrict__ fcw, unsigned char* __restrict__ img) {
  int gid = blockIdx.x * blockDim.x + threadIdx.x;
  int nthr = gridDim.x * blockDim.x;
  {
    short* W = (short*)(img + OFF_WIH0);
    for (int i = gid; i < 208 * 32; i += nthr) {
      int row = i >> 5, k = i & 31, u = row >> 2, q = row & 3;
      float v = (u < 50) ? wih0[(q * 50 + u) * 32 + k] : 0.0f;
      W[row * 32 + (k ^ ((row & 3) << 3))] = f2bf(v);
    }
  }
  {
    short* W = (short*)(img + OFF_WHH0);
    for (int i = gid; i < 208 * 64; i += nthr) {
      int row = i >> 6, k = i & 63, u = row >> 2, q = row & 3;
      float v = (u < 50 && k < 50) ? whh0[(q * 50 + u) * 50 + k] : 0.0f;
      W[row * 64 + (k ^ ((row & 7) << 3))] = f2bf(v);
    }
  }
  {
    short* W = (short*)(img + OFF_WIH1);
    for (int i = gid; i < 208 * 64; i += nthr) {
      int row = i >> 6, k = i & 63, u = row >> 2, q = row & 3;
      float v = (u < 50 && k < 50) ? wih1[(q * 50 + u) * 50 + k] : 0.0f;
      W[row * 64 + (k ^ ((row & 7) << 3))] = f2bf(v);
    }
  }
  {
    short* W = (short*)(img + OFF_WHH1);
    for (int i = gid; i < 208 * 64; i += nthr) {
      int row = i >> 6, k = i & 63, u = row >> 2, q = row & 3;
      float v = (u < 50 && k < 50) ? whh1[(q * 50 + u) * 50 + k] : 0.0f;
      W[row * 64 + (k ^ ((row & 7) << 3))] = f2bf(v);
    }
  }
  {
    float* B = (float*)(img + OFF_B0);
    for (int i = gid; i < 208; i += nthr) {
      int u = i >> 2, q = i & 3;
      B[i] = (u < 50) ? bih0[q * 50 + u] + bhh0[q * 50 + u] : 0.0f;
    }
  }
  {
    float* B = (float*)(img + OFF_B1);
    for (int i = gid; i < 208; i += nthr) {
      int u = i >> 2, q = i & 3;
      B[i] = (u < 50) ? bih1[q * 50 + u] + bhh1[q * 50 + u] : 0.0f;
    }
  }
  {
    float* F = (float*)(img + OFF_FCW);
    for (int i = gid; i < 52; i += nthr) F[i] = (i < 50) ? fcw[i] : 0.0f;
  }
}

// ================= fused 2-layer MFMA LSTM over 10 steps + FC =================
template <typename GT>
__global__ __launch_bounds__(512, 2) void k_lstm(const GT* __restrict__ gout,
    const unsigned char* __restrict__ img, const float* __restrict__ fcb_p,
    float* __restrict__ out, int N) {
  __shared__ __align__(16) unsigned char smem[160592];  // 95056 img + 8*8192 staging
  const int tid = threadIdx.x;
  {
    const uint4* s = (const uint4*)img;
    uint4* d = (uint4*)smem;
    for (int i = tid; i < IMG_BYTES / 16; i += 512) d[i] = s[i];
  }
  __syncthreads();
  const int lane = tid & 63, wid = tid >> 6;
  const int l15 = lane & 15, l4 = lane >> 4;
  const int swz7 = (l15 & 7) << 3, swz3 = (l15 & 3) << 3;
  const int node0 = blockIdx.x * 256 + wid * 32;

  const short* WIH0 = (const short*)(smem + OFF_WIH0);
  const short* WHH0 = (const short*)(smem + OFF_WHH0);
  const short* WIH1 = (const short*)(smem + OFF_WIH1);
  const short* WHH1 = (const short*)(smem + OFF_WHH1);
  const float* B0   = (const float*)(smem + OFF_B0);
  const float* B1   = (const float*)(smem + OFF_B1);
  const float* FCW  = (const float*)(smem + OFF_FCW);
  short* h0st = (short*)(smem + IMG_BYTES + wid * 8192);  // [32][64] bf16, swz
  short* h1st = h0st + 2048;

  {
    uint4 z; z.x = z.y = z.z = z.w = 0u;
    uint4* p = (uint4*)h0st;
    for (int i = lane; i < 512; i += 64) p[i] = z;
  }

  short8 gfrag[2];
#pragma unroll
  for (int v = 0; v < 2; ++v) {
    int node = node0 + v * 16 + l15;
    short8 t = {0, 0, 0, 0, 0, 0, 0, 0};
    if (node < N) t = load_gfrag(gout, (size_t)node * 32 + l4 * 8);
    gfrag[v] = t;
  }

  float c0[13][2], c1[13][2];
#pragma unroll
  for (int t = 0; t < 13; ++t) { c0[t][0]=0.f; c0[t][1]=0.f; c1[t][0]=0.f; c1[t][1]=0.f; }
  float facc[2] = {0.f, 0.f};

#pragma unroll 1
  for (int s = 0; s < 10; ++s) {
    short8 h0f[2][2], h1f[2][2];
#pragma unroll
    for (int c = 0; c < 2; ++c)
#pragma unroll
      for (int v = 0; v < 2; ++v) {
        int nl = v * 16 + l15;
        h0f[c][v] = *(const short8*)(h0st + nl * 64 + ((c * 32 + l4 * 8) ^ swz7));
        h1f[c][v] = *(const short8*)(h1st + nl * 64 + ((c * 32 + l4 * 8) ^ swz7));
      }
    // ---- layer 0 ----
#pragma unroll
    for (int t = 0; t < 13; ++t) {
      f32x4 bv = *(const f32x4*)(B0 + t * 16 + l4 * 4);
      int arow = (16 * t + l15);
      short8 aih = *(const short8*)(WIH0 + arow * 32 + ((l4 * 8) ^ swz3));
      short8 ah0 = *(const short8*)(WHH0 + arow * 64 + ((l4 * 8) ^ swz7));
      short8 ah1 = *(const short8*)(WHH0 + arow * 64 + ((32 + l4 * 8) ^ swz7));
#pragma unroll
      for (int v = 0; v < 2; ++v) {
        f32x4 acc = bv;
        acc = __builtin_amdgcn_mfma_f32_16x16x32_bf16(aih, gfrag[v], acc, 0, 0, 0);
        acc = __builtin_amdgcn_mfma_f32_16x16x32_bf16(ah0, h0f[0][v], acc, 0, 0, 0);
        acc = __builtin_amdgcn_mfma_f32_16x16x32_bf16(ah1, h0f[1][v], acc, 0, 0, 0);
        float iv = sigm(acc[0]), fv = sigm(acc[1]);
        float gv = tanh_(acc[2]), ov = sigm(acc[3]);
        float c = fv * c0[t][v] + iv * gv;
        c0[t][v] = c;
        float h = ov * tanh_(c);
        h0st[(v * 16 + l15) * 64 + ((4 * t + l4) ^ swz7)] = f2bf(h);
      }
    }
    short8 h0nf[2][2];
#pragma unroll
    for (int c = 0; c < 2; ++c)
#pragma unroll
      for (int v = 0; v < 2; ++v) {
        int nl = v * 16 + l15;
        h0nf[c][v] = *(const short8*)(h0st + nl * 64 + ((c * 32 + l4 * 8) ^ swz7));
      }
    // ---- layer 1 ----
#pragma unroll
    for (int t = 0; t < 13; ++t) {
      f32x4 bv = *(const f32x4*)(B1 + t * 16 + l4 * 4);
      int arow = (16 * t + l15);
      short8 ai0 = *(const short8*)(WIH1 + arow * 64 + ((l4 * 8) ^ swz7));
      short8 ai1 = *(const short8*)(WIH1 + arow * 64 + ((32 + l4 * 8) ^ swz7));
      short8 ah0 = *(const short8*)(WHH1 + arow * 64 + ((l4 * 8) ^ swz7));
      short8 ah1 = *(const short8*)(WHH1 + arow * 64 + ((32 + l4 * 8) ^ swz7));
#pragma unroll
      for (int v = 0; v < 2; ++v) {
        f32x4 acc = bv;
        acc = __builtin_amdgcn_mfma_f32_16x16x32_bf16(ai0, h0nf[0][v], acc, 0, 0, 0);
        acc = __builtin_amdgcn_mfma_f32_16x16x32_bf16(ai1, h0nf[1][v], acc, 0, 0, 0);
        acc = __builtin_amdgcn_mfma_f32_16x16x32_bf16(ah0, h1f[0][v], acc, 0, 0, 0);
        acc = __builtin_amdgcn_mfma_f32_16x16x32_bf16(ah1, h1f[1][v], acc, 0, 0, 0);
        float iv = sigm(acc[0]), fv = sigm(acc[1]);
        float gv = tanh_(acc[2]), ov = sigm(acc[3]);
        float c = fv * c1[t][v] + iv * gv;
        c1[t][v] = c;
        float h = ov * tanh_(c);
        h1st[(v * 16 + l15) * 64 + ((4 * t + l4) ^ swz7)] = f2bf(h);
        if (s == 9) {
          int u = 4 * t + l4;
          facc[v] += FCW[u] * h;
        }
      }
    }
  }
  float fcb = fcb_p[0];
#pragma unroll
  for (int v = 0; v < 2; ++v) {
    float r = facc[v];
    r += __shfl_xor(r, 16);
    r += __shfl_xor(r, 32);
    int node = node0 + v * 16 + l15;
    if (l4 == 0 && node < N) out[node] = r + fcb;
  }
}

// ================= host launcher =================
extern "C" void kernel_launch(void* const* d_in, const int* in_sizes, int n_in,
                              void* d_out, int out_size, void* d_ws, size_t ws_size,
                              hipStream_t stream) {
  const float* x    = (const float*)d_in[0];
  const float* Wg   = (const float*)d_in[1];
  const float* bg   = (const float*)d_in[2];
  const float* wih0 = (const float*)d_in[3];
  const float* whh0 = (const float*)d_in[4];
  const float* bih0 = (const float*)d_in[5];
  const float* bhh0 = (const float*)d_in[6];
  const float* wih1 = (const float*)d_in[7];
  const float* whh1 = (const float*)d_in[8];
  const float* bih1 = (const float*)d_in[9];
  const float* bhh1 = (const float*)d_in[10];
  const float* fcw  = (const float*)d_in[11];
  const float* fcb  = (const float*)d_in[12];
  const int*   edge = (const int*)d_in[13];
  int N = in_sizes[0] / 128;
  int E = in_sizes[13] / 2;

  char* ws = (char*)d_ws;
  size_t off = 0;
  auto take = [&](size_t b) {
    size_t o = off;
    off = (off + b + 255) & ~(size_t)255;
    return o;
  };
  // common allocations
  int*   rowst = (int*)(ws + take((size_t)N * 4));      // cnt -> excl-scan -> fill-ends
  float* dinv  = (float*)(ws + take((size_t)N * 4));
  int*   flag  = (int*)(ws + take(256));
  unsigned char* wimg = (unsigned char*)(ws + take(IMG_BYTES));

  // sizing for the three paths (beyond the common ~0.5 MB above)
  size_t base = off;
  size_t needA = base + ((size_t)N * 128 + 255 & ~(size_t)255)       // gout f32
               + ((size_t)E * 4 + 255 & ~(size_t)255)                 // csr u32
               + ((size_t)N * 128);                                   // hs f32
  size_t needB = base + ((size_t)N * 64 + 255 & ~(size_t)255)         // gout bf16
               + ((size_t)E * 2 + 255 & ~(size_t)255)                 // csr u16
               + ((size_t)N * 64);                                    // hs bf16
  bool canU16 = (N <= 65535);

  hipMemsetAsync(rowst, 0, (size_t)N * 4, stream);
  k_detect<<<1, 1, 0, stream>>>(edge, flag);
  k_count<<<(E + 255) / 256, 256, 0, stream>>>(edge, E, flag, rowst);
  k_dinv<<<(N + 255) / 256, 256, 0, stream>>>(rowst, dinv, N);
  k_prep<<<52, 256, 0, stream>>>(wih0, whh0, wih1, whh1, bih0, bhh0, bih1, bhh1,
                                 fcw, wimg);

  if (ws_size >= needA) {
    // ---- path A: f32 CSR ----
    float* gout = (float*)(ws + take((size_t)N * 128));
    int*   csr  = (int*)(ws + take((size_t)E * 4));
    float* hs   = (float*)(ws + take((size_t)N * 128));
    k_scan<<<1, 1024, 0, stream>>>(rowst, N);
    k_hs<float><<<(N + 63) / 64, 256, 0, stream>>>(x, Wg, dinv, hs, N);
    k_fill<int><<<(E + 255) / 256, 256, 0, stream>>>(edge, E, flag, rowst, csr);
    k_gather<float, float, int><<<(N + 3) / 4, 256, 0, stream>>>(
        csr, rowst, hs, dinv, bg, gout, N);
    k_lstm<float><<<(N + 255) / 256, 512, 0, stream>>>(gout, wimg, fcb,
                                                       (float*)d_out, N);
  } else if (canU16 && ws_size >= needB) {
    // ---- path B: bf16 CSR (fits the proven >=10.096 MB workspace) ----
    __hip_bfloat16* gout = (__hip_bfloat16*)(ws + take((size_t)N * 64));
    unsigned short* csr  = (unsigned short*)(ws + take((size_t)E * 2));
    __hip_bfloat16* hs   = (__hip_bfloat16*)(ws + take((size_t)N * 64));
    k_scan<<<1, 1024, 0, stream>>>(rowst, N);
    k_hs<__hip_bfloat16><<<(N + 63) / 64, 256, 0, stream>>>(x, Wg, dinv, hs, N);
    k_fill<unsigned short><<<(E + 255) / 256, 256, 0, stream>>>(edge, E, flag,
                                                                rowst, csr);
    k_gather<__hip_bfloat16, __hip_bfloat16, unsigned short>
        <<<(N + 3) / 4, 256, 0, stream>>>(csr, rowst, hs, dinv, bg, gout, N);
    k_lstm<__hip_bfloat16><<<(N + 255) / 256, 512, 0, stream>>>(gout, wimg, fcb,
                                                                (float*)d_out, N);
  } else {
    // ---- path C: scatter fallback (bf16 hs, f32 gout) ----
    float* gout = (float*)(ws + take((size_t)N * 128));
    __hip_bfloat16* hs = (__hip_bfloat16*)(ws + take((size_t)N * 64));
    hipMemsetAsync(gout, 0, (size_t)N * 128, stream);
    k_hs<__hip_bfloat16><<<(N + 63) / 64, 256, 0, stream>>>(x, Wg, dinv, hs, N);
    int sc_blocks = (int)(((long long)E * 8 + 255) / 256);
    k_scatter<__hip_bfloat16><<<sc_blocks, 256, 0, stream>>>(edge, E, flag, hs, gout);
    k_finish<__hip_bfloat16><<<(N * 32 + 255) / 256, 256, 0, stream>>>(
        hs, dinv, bg, gout, N);
    k_lstm<float><<<(N + 255) / 256, 512, 0, stream>>>(gout, wimg, fcb,
                                                       (float*)d_out, N);
  }
}

// Round 6
// 503.349 us; speedup vs baseline: 3.5483x; 1.1503x over previous
//
#include <hip/hip_runtime.h>
#include <hip/hip_bf16.h>

typedef __attribute__((ext_vector_type(8))) short short8;
typedef __attribute__((ext_vector_type(4))) float f32x4;

#define L2E 1.442695041f

__device__ __forceinline__ float sigm(float x) {
  return 1.0f / (1.0f + __expf(-x));
}
__device__ __forceinline__ short f2bf(float f) {
  union { __hip_bfloat16 b; short s; } u;
  u.b = __float2bfloat16(f);
  return u.s;
}

// ---- f32/bf16 storage accessors ----
__device__ __forceinline__ float ldh(const float* p, size_t i) { return p[i]; }
__device__ __forceinline__ float ldh(const __hip_bfloat16* p, size_t i) {
  return __bfloat162float(p[i]);
}
__device__ __forceinline__ void sth(float* p, size_t i, float v) { p[i] = v; }
__device__ __forceinline__ void sth(__hip_bfloat16* p, size_t i, float v) {
  p[i] = __float2bfloat16(v);
}

__device__ __forceinline__ short8 load_gfrag(const float* g, size_t base) {
  const float4* gp = (const float4*)(g + base);
  float4 a = gp[0], b = gp[1];
  short8 t;
  t[0]=f2bf(a.x); t[1]=f2bf(a.y); t[2]=f2bf(a.z); t[3]=f2bf(a.w);
  t[4]=f2bf(b.x); t[5]=f2bf(b.y); t[6]=f2bf(b.z); t[7]=f2bf(b.w);
  return t;
}
__device__ __forceinline__ short8 load_gfrag(const __hip_bfloat16* g, size_t base) {
  return *(const short8*)(g + base);
}

// ---------------- weight image layout (bytes) ----------------
#define OFF_WIH0 0        // bf16 [208][32], swz (row&3)<<3, exp2-prescaled
#define OFF_WHH0 13312    // bf16 [208][64], swz (row&7)<<3, exp2-prescaled
#define OFF_WIH1 39936
#define OFF_WHH1 66560
#define OFF_B0   93184    // f32 [208], exp2-prescaled
#define OFF_B1   94016
#define OFF_FCW  94848    // f32 [52] (raw)
#define IMG_BYTES 95056

// ================= edge dtype autodetect =================
__global__ void k_detect(const int* __restrict__ ei, int* __restrict__ flag) {
  if (threadIdx.x == 0 && blockIdx.x == 0) {
    int odd_nz = 0, even_nz = 0;
    for (int i = 0; i < 128; ++i) {
      odd_nz |= (ei[2 * i + 1] != 0);
      even_nz |= (ei[2 * i] != 0);
    }
    *flag = (even_nz && !odd_nz) ? 1 : 0;
  }
}

// ================= GCN =================

__global__ void k_count(const int* __restrict__ ei, int E,
                        const int* __restrict__ flag, int* __restrict__ cnt) {
  int e = blockIdx.x * blockDim.x + threadIdx.x;
  if (e < E) {
    int d = (*flag) ? ei[2 * (E + e)] : ei[E + e];
    atomicAdd(&cnt[d], 1);
  }
}

__global__ void k_dinv(const int* __restrict__ cnt, float* __restrict__ dinv, int N) {
  int i = blockIdx.x * blockDim.x + threadIdx.x;
  if (i < N) dinv[i] = rsqrtf((float)cnt[i] + 1.0f);
}

// in-place exclusive scan over counts; also emits dinv = rsqrt(cnt+1)
__global__ __launch_bounds__(1024) void k_scan(int* __restrict__ a,
                                               float* __restrict__ dinv, int N) {
  __shared__ int part[1024];
  int t = threadIdx.x;
  int chunk = (N + 1023) >> 10;
  int lo = t * chunk, hi = min(lo + chunk, N);
  int ssum = 0;
  for (int i = lo; i < hi; ++i) {
    int c = a[i];
    dinv[i] = rsqrtf((float)c + 1.0f);
    ssum += c;
  }
  part[t] = ssum;
  __syncthreads();
  for (int off = 1; off < 1024; off <<= 1) {
    int v = (t >= off) ? part[t - off] : 0;
    __syncthreads();
    part[t] += v;
    __syncthreads();
  }
  int base = part[t] - ssum;
  for (int i = lo; i < hi; ++i) {
    int c = a[i];
    a[i] = base;
    base += c;
  }
}

template <typename CT>
__global__ void k_fill(const int* __restrict__ ei, int E,
                       const int* __restrict__ flag,
                       int* __restrict__ rowst, CT* __restrict__ csr) {
  int e = blockIdx.x * blockDim.x + threadIdx.x;
  if (e < E) {
    int is64 = *flag;
    int s = is64 ? ei[2 * e] : ei[e];
    int d = is64 ? ei[2 * (E + e)] : ei[E + e];
    int p = atomicAdd(&rowst[d], 1);
    csr[p] = (CT)s;
  }
}

// hs[n][g] = (x[n] @ W)[g] * dinv[n]
template <typename HT>
__global__ __launch_bounds__(256) void k_hs(const float* __restrict__ x,
                                            const float* __restrict__ Wg,
                                            const float* __restrict__ dinv,
                                            HT* __restrict__ hs, int N) {
  __shared__ __align__(16) float xt[64][132];
  __shared__ __align__(16) float Wl[128][32];
  int tid = threadIdx.x;
  int nb = blockIdx.x * 64;
  for (int i = tid; i < 4096; i += 256) Wl[i >> 5][i & 31] = Wg[i];
  const float4* xv = (const float4*)x;
  for (int i = tid; i < 2048; i += 256) {
    int r = i >> 5, c = i & 31;
    float4 v = make_float4(0.f, 0.f, 0.f, 0.f);
    if (nb + r < N) v = xv[(size_t)(nb + r) * 32 + c];
    *(float4*)&xt[r][c * 4] = v;
  }
  __syncthreads();
  int nl = tid >> 2, gq = (tid & 3) * 8;
  float a[8];
#pragma unroll
  for (int j = 0; j < 8; ++j) a[j] = 0.f;
  for (int k = 0; k < 128; ++k) {
    float xk = xt[nl][k];
#pragma unroll
    for (int j = 0; j < 8; ++j) a[j] += xk * Wl[k][gq + j];
  }
  int n = nb + nl;
  if (n < N) {
    float d = dinv[n];
#pragma unroll
    for (int j = 0; j < 8; ++j) sth(hs, (size_t)n * 32 + gq + j, a[j] * d);
  }
}

// one wave per node; index-broadcast gather: all hs loads independent
template <typename HT, typename GT, typename CT>
__global__ void k_gather(const CT* __restrict__ csr, const int* __restrict__ rowst,
                         const HT* __restrict__ hs, const float* __restrict__ dinv,
                         const float* __restrict__ bg, GT* __restrict__ gout,
                         int N) {
  int w = (blockIdx.x * blockDim.x + threadIdx.x) >> 6;
  if (w >= N) return;
  int l = threadIdx.x & 63;
  int g = l & 31, j = l >> 5;
  int end = rowst[w];
  int start = (w == 0) ? 0 : rowst[w - 1];
  int deg = end - start;
  int dmax = min(deg, 64);
  // coalesced preload of up to 64 indices (one per lane)
  int idx = (l < deg) ? (int)csr[start + l] : 0;
  float acc = 0.0f;
#pragma unroll 1
  for (int base = 0; base < 64; base += 16) {
    if (base >= dmax) break;
#pragma unroll
    for (int i = 0; i < 8; ++i) {
      int e = base + 2 * i + j;
      int src = __shfl(idx, e);
      float v = ldh(hs, (size_t)src * 32 + g);
      acc += (e < dmax) ? v : 0.0f;
    }
  }
  // rare tail (deg > 64)
  for (int k = start + 64 + j; k < end; k += 2)
    acc += ldh(hs, (size_t)csr[k] * 32 + g);
  acc += __shfl_xor(acc, 32);
  if (j == 0) {
    float v = (acc + ldh(hs, (size_t)w * 32 + g)) * dinv[w] + bg[g];
    sth(gout, (size_t)w * 32 + g, v);
  }
}

// ---- scatter fallback ----
template <typename HT>
__global__ void k_scatter(const int* __restrict__ ei, int E,
                          const int* __restrict__ flag,
                          const HT* __restrict__ hs, float* __restrict__ gout) {
  long long gid = (long long)blockIdx.x * blockDim.x + threadIdx.x;
  int e = (int)(gid >> 3), part = (int)(gid & 7);
  if (e >= E) return;
  int is64 = *flag;
  int s = is64 ? ei[2 * e] : ei[e];
  int d = is64 ? ei[2 * (E + e)] : ei[E + e];
  int b = part * 4;
  float* gp = gout + (size_t)d * 32 + b;
  size_t hp = (size_t)s * 32 + b;
  atomicAdd(gp + 0, ldh(hs, hp + 0));
  atomicAdd(gp + 1, ldh(hs, hp + 1));
  atomicAdd(gp + 2, ldh(hs, hp + 2));
  atomicAdd(gp + 3, ldh(hs, hp + 3));
}
template <typename HT>
__global__ void k_finish(const HT* __restrict__ hs, const float* __restrict__ dinv,
                         const float* __restrict__ bg, float* __restrict__ gout,
                         int N) {
  int gid = blockIdx.x * blockDim.x + threadIdx.x;
  if (gid < N * 32) {
    int n = gid >> 5, g = gid & 31;
    gout[gid] = (gout[gid] + ldh(hs, (size_t)gid)) * dinv[n] + bg[g];
  }
}

// ================= weight image prep (exp2-prescaled) =================
// perm row 4u+q = source gate row q*50+u. Scales: i,f,o rows by -log2(e)
// (folds negation for sigm=rcp(1+exp2(x))), g rows by +2*log2(e).
__global__ void k_prep(const float* __restrict__ wih0, const float* __restrict__ whh0,
                       const float* __restrict__ wih1, const float* __restrict__ whh1,
                       const float* __restrict__ bih0, const float* __restrict__ bhh0,
                       const float* __restrict__ bih1, const float* __restrict__ bhh1,
                       const float* __restrict__ fcw, unsigned char* __restrict__ img) {
  int gid = blockIdx.x * blockDim.x + threadIdx.x;
  int nthr = gridDim.x * blockDim.x;
  {
    short* W = (short*)(img + OFF_WIH0);
    for (int i = gid; i < 208 * 32; i += nthr) {
      int row = i >> 5, k = i & 31, u = row >> 2, q = row & 3;
      float sc = (q == 2) ? 2.0f * L2E : -L2E;
      float v = (u < 50) ? wih0[(q * 50 + u) * 32 + k] * sc : 0.0f;
      W[row * 32 + (k ^ ((row & 3) << 3))] = f2bf(v);
    }
  }
  {
    short* W = (short*)(img + OFF_WHH0);
    for (int i = gid; i < 208 * 64; i += nthr) {
      int row = i >> 6, k = i & 63, u = row >> 2, q = row & 3;
      float sc = (q == 2) ? 2.0f * L2E : -L2E;
      float v = (u < 50 && k < 50) ? whh0[(q * 50 + u) * 50 + k] * sc : 0.0f;
      W[row * 64 + (k ^ ((row & 7) << 3))] = f2bf(v);
    }
  }
  {
    short* W = (short*)(img + OFF_WIH1);
    for (int i = gid; i < 208 * 64; i += nthr) {
      int row = i >> 6, k = i & 63, u = row >> 2, q = row & 3;
      float sc = (q == 2) ? 2.0f * L2E : -L2E;
      float v = (u < 50 && k < 50) ? wih1[(q * 50 + u) * 50 + k] * sc : 0.0f;
      W[row * 64 + (k ^ ((row & 7) << 3))] = f2bf(v);
    }
  }
  {
    short* W = (short*)(img + OFF_WHH1);
    for (int i = gid; i < 208 * 64; i += nthr) {
      int row = i >> 6, k = i & 63, u = row >> 2, q = row & 3;
      float sc = (q == 2) ? 2.0f * L2E : -L2E;
      float v = (u < 50 && k < 50) ? whh1[(q * 50 + u) * 50 + k] * sc : 0.0f;
      W[row * 64 + (k ^ ((row & 7) << 3))] = f2bf(v);
    }
  }
  {
    float* B = (float*)(img + OFF_B0);
    for (int i = gid; i < 208; i += nthr) {
      int u = i >> 2, q = i & 3;
      float sc = (q == 2) ? 2.0f * L2E : -L2E;
      B[i] = (u < 50) ? (bih0[q * 50 + u] + bhh0[q * 50 + u]) * sc : 0.0f;
    }
  }
  {
    float* B = (float*)(img + OFF_B1);
    for (int i = gid; i < 208; i += nthr) {
      int u = i >> 2, q = i & 3;
      float sc = (q == 2) ? 2.0f * L2E : -L2E;
      B[i] = (u < 50) ? (bih1[q * 50 + u] + bhh1[q * 50 + u]) * sc : 0.0f;
    }
  }
  {
    float* F = (float*)(img + OFF_FCW);
    for (int i = gid; i < 52; i += nthr) F[i] = (i < 50) ? fcw[i] : 0.0f;
  }
}

// exp2-domain gates: acc = (î,f̂,ĝ,ô) prescaled; cp = c-state in/out
__device__ __forceinline__ float gate_update(const f32x4& acc, float& cp) {
  float ei = __builtin_amdgcn_exp2f(acc[0]);
  float ef = __builtin_amdgcn_exp2f(acc[1]);
  float eo = __builtin_amdgcn_exp2f(acc[3]);
  float iv = __builtin_amdgcn_rcpf(1.0f + ei);
  float fv = __builtin_amdgcn_rcpf(1.0f + ef);
  float ov = __builtin_amdgcn_rcpf(1.0f + eo);
  float eg = __builtin_amdgcn_exp2f(fminf(acc[2], 80.0f));
  float gv = (eg - 1.0f) * __builtin_amdgcn_rcpf(eg + 1.0f);
  float c = fv * cp + iv * gv;
  cp = c;
  float Ec = __builtin_amdgcn_exp2f(c * (2.0f * L2E));
  float th = (Ec - 1.0f) * __builtin_amdgcn_rcpf(Ec + 1.0f);
  return ov * th;  // h
}

// ================= fused 2-layer MFMA LSTM over 10 steps + FC =================
template <typename GT>
__global__ __launch_bounds__(512, 2) void k_lstm(const GT* __restrict__ gout,
    const unsigned char* __restrict__ img, const float* __restrict__ fcb_p,
    float* __restrict__ out, int N) {
  __shared__ __align__(16) unsigned char smem[160592];
  const int tid = threadIdx.x;
  {
    const uint4* s = (const uint4*)img;
    uint4* d = (uint4*)smem;
    for (int i = tid; i < IMG_BYTES / 16; i += 512) d[i] = s[i];
  }
  __syncthreads();
  const int lane = tid & 63, wid = tid >> 6;
  const int l15 = lane & 15, l4 = lane >> 4;
  const int swz7 = (l15 & 7) << 3, swz3 = (l15 & 3) << 3;
  const int node0 = blockIdx.x * 256 + wid * 32;

  const short* WIH0 = (const short*)(smem + OFF_WIH0);
  const short* WHH0 = (const short*)(smem + OFF_WHH0);
  const short* WIH1 = (const short*)(smem + OFF_WIH1);
  const short* WHH1 = (const short*)(smem + OFF_WHH1);
  const float* B0   = (const float*)(smem + OFF_B0);
  const float* B1   = (const float*)(smem + OFF_B1);
  const float* FCW  = (const float*)(smem + OFF_FCW);
  short* h0st = (short*)(smem + IMG_BYTES + wid * 8192);
  short* h1st = h0st + 2048;

  {
    uint4 z; z.x = z.y = z.z = z.w = 0u;
    uint4* p = (uint4*)h0st;
    for (int i = lane; i < 512; i += 64) p[i] = z;
  }

  short8 gfrag[2];
#pragma unroll
  for (int v = 0; v < 2; ++v) {
    int node = node0 + v * 16 + l15;
    short8 t = {0, 0, 0, 0, 0, 0, 0, 0};
    if (node < N) t = load_gfrag(gout, (size_t)node * 32 + l4 * 8);
    gfrag[v] = t;
  }

  // step-invariant WIH0 A-fragments cached in registers (13 x short8)
  short8 wih0r[13];
#pragma unroll
  for (int t = 0; t < 13; ++t)
    wih0r[t] = *(const short8*)(WIH0 + (16 * t + l15) * 32 + ((l4 * 8) ^ swz3));

  float c0[13][2], c1[13][2];
#pragma unroll
  for (int t = 0; t < 13; ++t) { c0[t][0]=0.f; c0[t][1]=0.f; c1[t][0]=0.f; c1[t][1]=0.f; }
  float facc[2] = {0.f, 0.f};

#pragma unroll 1
  for (int s = 0; s < 10; ++s) {
    short8 h0f[2][2], h1f[2][2];
#pragma unroll
    for (int c = 0; c < 2; ++c)
#pragma unroll
      for (int v = 0; v < 2; ++v) {
        int nl = v * 16 + l15;
        h0f[c][v] = *(const short8*)(h0st + nl * 64 + ((c * 32 + l4 * 8) ^ swz7));
        h1f[c][v] = *(const short8*)(h1st + nl * 64 + ((c * 32 + l4 * 8) ^ swz7));
      }
    // ---- layer 0 ----
#pragma unroll
    for (int t = 0; t < 13; ++t) {
      f32x4 bv = *(const f32x4*)(B0 + t * 16 + l4 * 4);
      int arow = (16 * t + l15);
      short8 ah0 = *(const short8*)(WHH0 + arow * 64 + ((l4 * 8) ^ swz7));
      short8 ah1 = *(const short8*)(WHH0 + arow * 64 + ((32 + l4 * 8) ^ swz7));
#pragma unroll
      for (int v = 0; v < 2; ++v) {
        f32x4 acc = bv;
        acc = __builtin_amdgcn_mfma_f32_16x16x32_bf16(wih0r[t], gfrag[v], acc, 0, 0, 0);
        acc = __builtin_amdgcn_mfma_f32_16x16x32_bf16(ah0, h0f[0][v], acc, 0, 0, 0);
        acc = __builtin_amdgcn_mfma_f32_16x16x32_bf16(ah1, h0f[1][v], acc, 0, 0, 0);
        float h = gate_update(acc, c0[t][v]);
        h0st[(v * 16 + l15) * 64 + ((4 * t + l4) ^ swz7)] = f2bf(h);
      }
    }
    short8 h0nf[2][2];
#pragma unroll
    for (int c = 0; c < 2; ++c)
#pragma unroll
      for (int v = 0; v < 2; ++v) {
        int nl = v * 16 + l15;
        h0nf[c][v] = *(const short8*)(h0st + nl * 64 + ((c * 32 + l4 * 8) ^ swz7));
      }
    // ---- layer 1 ----
#pragma unroll
    for (int t = 0; t < 13; ++t) {
      f32x4 bv = *(const f32x4*)(B1 + t * 16 + l4 * 4);
      int arow = (16 * t + l15);
      short8 ai0 = *(const short8*)(WIH1 + arow * 64 + ((l4 * 8) ^ swz7));
      short8 ai1 = *(const short8*)(WIH1 + arow * 64 + ((32 + l4 * 8) ^ swz7));
      short8 ah0 = *(const short8*)(WHH1 + arow * 64 + ((l4 * 8) ^ swz7));
      short8 ah1 = *(const short8*)(WHH1 + arow * 64 + ((32 + l4 * 8) ^ swz7));
#pragma unroll
      for (int v = 0; v < 2; ++v) {
        f32x4 acc = bv;
        acc = __builtin_amdgcn_mfma_f32_16x16x32_bf16(ai0, h0nf[0][v], acc, 0, 0, 0);
        acc = __builtin_amdgcn_mfma_f32_16x16x32_bf16(ai1, h0nf[1][v], acc, 0, 0, 0);
        acc = __builtin_amdgcn_mfma_f32_16x16x32_bf16(ah0, h1f[0][v], acc, 0, 0, 0);
        acc = __builtin_amdgcn_mfma_f32_16x16x32_bf16(ah1, h1f[1][v], acc, 0, 0, 0);
        float h = gate_update(acc, c1[t][v]);
        h1st[(v * 16 + l15) * 64 + ((4 * t + l4) ^ swz7)] = f2bf(h);
        if (s == 9) {
          int u = 4 * t + l4;
          facc[v] += FCW[u] * h;
        }
      }
    }
  }
  float fcb = fcb_p[0];
#pragma unroll
  for (int v = 0; v < 2; ++v) {
    float r = facc[v];
    r += __shfl_xor(r, 16);
    r += __shfl_xor(r, 32);
    int node = node0 + v * 16 + l15;
    if (l4 == 0 && node < N) out[node] = r + fcb;
  }
}

// ================= host launcher =================
extern "C" void kernel_launch(void* const* d_in, const int* in_sizes, int n_in,
                              void* d_out, int out_size, void* d_ws, size_t ws_size,
                              hipStream_t stream) {
  const float* x    = (const float*)d_in[0];
  const float* Wg   = (const float*)d_in[1];
  const float* bg   = (const float*)d_in[2];
  const float* wih0 = (const float*)d_in[3];
  const float* whh0 = (const float*)d_in[4];
  const float* bih0 = (const float*)d_in[5];
  const float* bhh0 = (const float*)d_in[6];
  const float* wih1 = (const float*)d_in[7];
  const float* whh1 = (const float*)d_in[8];
  const float* bih1 = (const float*)d_in[9];
  const float* bhh1 = (const float*)d_in[10];
  const float* fcw  = (const float*)d_in[11];
  const float* fcb  = (const float*)d_in[12];
  const int*   edge = (const int*)d_in[13];
  int N = in_sizes[0] / 128;
  int E = in_sizes[13] / 2;

  char* ws = (char*)d_ws;
  size_t off = 0;
  auto take = [&](size_t b) {
    size_t o = off;
    off = (off + b + 255) & ~(size_t)255;
    return o;
  };
  int*   rowst = (int*)(ws + take((size_t)N * 4));
  float* dinv  = (float*)(ws + take((size_t)N * 4));
  int*   flag  = (int*)(ws + take(256));
  unsigned char* wimg = (unsigned char*)(ws + take(IMG_BYTES));

  size_t base = off;
  size_t needA = base + (((size_t)N * 128 + 255) & ~(size_t)255)
               + (((size_t)E * 4 + 255) & ~(size_t)255)
               + ((size_t)N * 128);
  size_t needB = base + (((size_t)N * 64 + 255) & ~(size_t)255)
               + (((size_t)E * 2 + 255) & ~(size_t)255)
               + ((size_t)N * 64);
  bool canU16 = (N <= 65535);

  hipMemsetAsync(rowst, 0, (size_t)N * 4, stream);
  k_detect<<<1, 1, 0, stream>>>(edge, flag);
  k_count<<<(E + 255) / 256, 256, 0, stream>>>(edge, E, flag, rowst);
  k_prep<<<52, 256, 0, stream>>>(wih0, whh0, wih1, whh1, bih0, bhh0, bih1, bhh1,
                                 fcw, wimg);

  if (ws_size >= needA) {
    float* gout = (float*)(ws + take((size_t)N * 128));
    int*   csr  = (int*)(ws + take((size_t)E * 4));
    float* hs   = (float*)(ws + take((size_t)N * 128));
    k_scan<<<1, 1024, 0, stream>>>(rowst, dinv, N);
    k_hs<float><<<(N + 63) / 64, 256, 0, stream>>>(x, Wg, dinv, hs, N);
    k_fill<int><<<(E + 255) / 256, 256, 0, stream>>>(edge, E, flag, rowst, csr);
    k_gather<float, float, int><<<(N + 3) / 4, 256, 0, stream>>>(
        csr, rowst, hs, dinv, bg, gout, N);
    k_lstm<float><<<(N + 255) / 256, 512, 0, stream>>>(gout, wimg, fcb,
                                                       (float*)d_out, N);
  } else if (canU16 && ws_size >= needB) {
    __hip_bfloat16* gout = (__hip_bfloat16*)(ws + take((size_t)N * 64));
    unsigned short* csr  = (unsigned short*)(ws + take((size_t)E * 2));
    __hip_bfloat16* hs   = (__hip_bfloat16*)(ws + take((size_t)N * 64));
    k_scan<<<1, 1024, 0, stream>>>(rowst, dinv, N);
    k_hs<__hip_bfloat16><<<(N + 63) / 64, 256, 0, stream>>>(x, Wg, dinv, hs, N);
    k_fill<unsigned short><<<(E + 255) / 256, 256, 0, stream>>>(edge, E, flag,
                                                                rowst, csr);
    k_gather<__hip_bfloat16, __hip_bfloat16, unsigned short>
        <<<(N + 3) / 4, 256, 0, stream>>>(csr, rowst, hs, dinv, bg, gout, N);
    k_lstm<__hip_bfloat16><<<(N + 255) / 256, 512, 0, stream>>>(gout, wimg, fcb,
                                                                (float*)d_out, N);
  } else {
    float* gout = (float*)(ws + take((size_t)N * 128));
    __hip_bfloat16* hs = (__hip_bfloat16*)(ws + take((size_t)N * 64));
    hipMemsetAsync(gout, 0, (size_t)N * 128, stream);
    k_dinv<<<(N + 255) / 256, 256, 0, stream>>>(rowst, dinv, N);
    k_hs<__hip_bfloat16><<<(N + 63) / 64, 256, 0, stream>>>(x, Wg, dinv, hs, N);
    int sc_blocks = (int)(((long long)E * 8 + 255) / 256);
    k_scatter<__hip_bfloat16><<<sc_blocks, 256, 0, stream>>>(edge, E, flag, hs, gout);
    k_finish<__hip_bfloat16><<<(N * 32 + 255) / 256, 256, 0, stream>>>(
        hs, dinv, bg, gout, N);
    k_lstm<float><<<(N + 255) / 256, 512, 0, stream>>>(gout, wimg, fcb,
                                                       (float*)d_out, N);
  }
}

// Round 7
// 474.948 us; speedup vs baseline: 3.7604x; 1.0598x over previous
//
#include <hip/hip_runtime.h>
#include <hip/hip_bf16.h>

typedef __attribute__((ext_vector_type(8))) short short8;
typedef __attribute__((ext_vector_type(4))) float f32x4;

#define L2E 1.442695041f

__device__ __forceinline__ short f2bf(float f) {
  union { __hip_bfloat16 b; short s; } u;
  u.b = __float2bfloat16(f);
  return u.s;
}

// ---- f32/bf16 storage accessors ----
__device__ __forceinline__ float ldh(const float* p, size_t i) { return p[i]; }
__device__ __forceinline__ float ldh(const __hip_bfloat16* p, size_t i) {
  return __bfloat162float(p[i]);
}
__device__ __forceinline__ void sth(float* p, size_t i, float v) { p[i] = v; }
__device__ __forceinline__ void sth(__hip_bfloat16* p, size_t i, float v) {
  p[i] = __float2bfloat16(v);
}

__device__ __forceinline__ short8 load_gfrag(const float* g, size_t base) {
  const float4* gp = (const float4*)(g + base);
  float4 a = gp[0], b = gp[1];
  short8 t;
  t[0]=f2bf(a.x); t[1]=f2bf(a.y); t[2]=f2bf(a.z); t[3]=f2bf(a.w);
  t[4]=f2bf(b.x); t[5]=f2bf(b.y); t[6]=f2bf(b.z); t[7]=f2bf(b.w);
  return t;
}
__device__ __forceinline__ short8 load_gfrag(const __hip_bfloat16* g, size_t base) {
  return *(const short8*)(g + base);
}

// ---------------- weight image layout (bytes) ----------------
#define OFF_WIH0 0        // bf16 [208][32], swz (row&3)<<3, exp2-prescaled
#define OFF_WHH0 13312    // bf16 [208][64], swz (row&7)<<3, exp2-prescaled
#define OFF_WIH1 39936
#define OFF_WHH1 66560
#define OFF_B0   93184    // f32 [208], exp2-prescaled
#define OFF_B1   94016
#define OFF_FCW  94848    // f32 [52] (raw)
#define IMG_BYTES 95056

// ================= edge dtype autodetect =================
__global__ void k_detect(const int* __restrict__ ei, int* __restrict__ flag) {
  if (threadIdx.x == 0 && blockIdx.x == 0) {
    int odd_nz = 0, even_nz = 0;
    for (int i = 0; i < 128; ++i) {
      odd_nz |= (ei[2 * i + 1] != 0);
      even_nz |= (ei[2 * i] != 0);
    }
    *flag = (even_nz && !odd_nz) ? 1 : 0;
  }
}

// ================= GCN =================

__global__ void k_count(const int* __restrict__ ei, int E,
                        const int* __restrict__ flag, int* __restrict__ cnt) {
  int e = blockIdx.x * blockDim.x + threadIdx.x;
  if (e < E) {
    int d = (*flag) ? ei[2 * (E + e)] : ei[E + e];
    atomicAdd(&cnt[d], 1);
  }
}

__global__ void k_dinv(const int* __restrict__ cnt, float* __restrict__ dinv, int N) {
  int i = blockIdx.x * blockDim.x + threadIdx.x;
  if (i < N) dinv[i] = rsqrtf((float)cnt[i] + 1.0f);
}

// in-place exclusive scan over counts; also emits dinv = rsqrt(cnt+1)
__global__ __launch_bounds__(1024) void k_scan(int* __restrict__ a,
                                               float* __restrict__ dinv, int N) {
  __shared__ int part[1024];
  int t = threadIdx.x;
  int chunk = (N + 1023) >> 10;
  int lo = t * chunk, hi = min(lo + chunk, N);
  int ssum = 0;
  for (int i = lo; i < hi; ++i) {
    int c = a[i];
    dinv[i] = rsqrtf((float)c + 1.0f);
    ssum += c;
  }
  part[t] = ssum;
  __syncthreads();
  for (int off = 1; off < 1024; off <<= 1) {
    int v = (t >= off) ? part[t - off] : 0;
    __syncthreads();
    part[t] += v;
    __syncthreads();
  }
  int base = part[t] - ssum;
  for (int i = lo; i < hi; ++i) {
    int c = a[i];
    a[i] = base;
    base += c;
  }
}

// dst-range pass: only materialize edges with dst in [lo,hi) so the active
// csr write-window (~E/8*4B) stays L2-resident -> full-line write coalescing
template <typename CT>
__global__ void k_fill(const int* __restrict__ ei, int E,
                       const int* __restrict__ flag,
                       int* __restrict__ rowst, CT* __restrict__ csr,
                       int lo, int hi) {
  int e = blockIdx.x * blockDim.x + threadIdx.x;
  if (e < E) {
    int is64 = *flag;
    int d = is64 ? ei[2 * (E + e)] : ei[E + e];
    if (d >= lo && d < hi) {
      int s = is64 ? ei[2 * e] : ei[e];
      int p = atomicAdd(&rowst[d], 1);
      csr[p] = (CT)s;
    }
  }
}

// hs[n][g] = (x[n] @ W)[g] * dinv[n]
template <typename HT>
__global__ __launch_bounds__(256) void k_hs(const float* __restrict__ x,
                                            const float* __restrict__ Wg,
                                            const float* __restrict__ dinv,
                                            HT* __restrict__ hs, int N) {
  __shared__ __align__(16) float xt[64][132];
  __shared__ __align__(16) float Wl[128][32];
  int tid = threadIdx.x;
  int nb = blockIdx.x * 64;
  for (int i = tid; i < 4096; i += 256) Wl[i >> 5][i & 31] = Wg[i];
  const float4* xv = (const float4*)x;
  for (int i = tid; i < 2048; i += 256) {
    int r = i >> 5, c = i & 31;
    float4 v = make_float4(0.f, 0.f, 0.f, 0.f);
    if (nb + r < N) v = xv[(size_t)(nb + r) * 32 + c];
    *(float4*)&xt[r][c * 4] = v;
  }
  __syncthreads();
  int nl = tid >> 2, gq = (tid & 3) * 8;
  float a[8];
#pragma unroll
  for (int j = 0; j < 8; ++j) a[j] = 0.f;
  for (int k = 0; k < 128; ++k) {
    float xk = xt[nl][k];
#pragma unroll
    for (int j = 0; j < 8; ++j) a[j] += xk * Wl[k][gq + j];
  }
  int n = nb + nl;
  if (n < N) {
    float d = dinv[n];
#pragma unroll
    for (int j = 0; j < 8; ++j) sth(hs, (size_t)n * 32 + gq + j, a[j] * d);
  }
}

// one wave per node; index-broadcast gather: all hs loads independent
template <typename HT, typename GT, typename CT>
__global__ void k_gather(const CT* __restrict__ csr, const int* __restrict__ rowst,
                         const HT* __restrict__ hs, const float* __restrict__ dinv,
                         const float* __restrict__ bg, GT* __restrict__ gout,
                         int N) {
  int w = (blockIdx.x * blockDim.x + threadIdx.x) >> 6;
  if (w >= N) return;
  int l = threadIdx.x & 63;
  int g = l & 31, j = l >> 5;
  int end = rowst[w];
  int start = (w == 0) ? 0 : rowst[w - 1];
  int deg = end - start;
  int dmax = min(deg, 64);
  int idx = (l < deg) ? (int)csr[start + l] : 0;
  float acc = 0.0f;
#pragma unroll 1
  for (int base = 0; base < 64; base += 16) {
    if (base >= dmax) break;
#pragma unroll
    for (int i = 0; i < 8; ++i) {
      int e = base + 2 * i + j;
      int src = __shfl(idx, e);
      float v = ldh(hs, (size_t)src * 32 + g);
      acc += (e < dmax) ? v : 0.0f;
    }
  }
  for (int k = start + 64 + j; k < end; k += 2)
    acc += ldh(hs, (size_t)csr[k] * 32 + g);
  acc += __shfl_xor(acc, 32);
  if (j == 0) {
    float v = (acc + ldh(hs, (size_t)w * 32 + g)) * dinv[w] + bg[g];
    sth(gout, (size_t)w * 32 + g, v);
  }
}

// ---- scatter fallback ----
template <typename HT>
__global__ void k_scatter(const int* __restrict__ ei, int E,
                          const int* __restrict__ flag,
                          const HT* __restrict__ hs, float* __restrict__ gout) {
  long long gid = (long long)blockIdx.x * blockDim.x + threadIdx.x;
  int e = (int)(gid >> 3), part = (int)(gid & 7);
  if (e >= E) return;
  int is64 = *flag;
  int s = is64 ? ei[2 * e] : ei[e];
  int d = is64 ? ei[2 * (E + e)] : ei[E + e];
  int b = part * 4;
  float* gp = gout + (size_t)d * 32 + b;
  size_t hp = (size_t)s * 32 + b;
  atomicAdd(gp + 0, ldh(hs, hp + 0));
  atomicAdd(gp + 1, ldh(hs, hp + 1));
  atomicAdd(gp + 2, ldh(hs, hp + 2));
  atomicAdd(gp + 3, ldh(hs, hp + 3));
}
template <typename HT>
__global__ void k_finish(const HT* __restrict__ hs, const float* __restrict__ dinv,
                         const float* __restrict__ bg, float* __restrict__ gout,
                         int N) {
  int gid = blockIdx.x * blockDim.x + threadIdx.x;
  if (gid < N * 32) {
    int n = gid >> 5, g = gid & 31;
    gout[gid] = (gout[gid] + ldh(hs, (size_t)gid)) * dinv[n] + bg[g];
  }
}

// ================= weight image prep (exp2-prescaled) =================
__global__ void k_prep(const float* __restrict__ wih0, const float* __restrict__ whh0,
                       const float* __restrict__ wih1, const float* __restrict__ whh1,
                       const float* __restrict__ bih0, const float* __restrict__ bhh0,
                       const float* __restrict__ bih1, const float* __restrict__ bhh1,
                       const float* __restrict__ fcw, unsigned char* __restrict__ img) {
  int gid = blockIdx.x * blockDim.x + threadIdx.x;
  int nthr = gridDim.x * blockDim.x;
  {
    short* W = (short*)(img + OFF_WIH0);
    for (int i = gid; i < 208 * 32; i += nthr) {
      int row = i >> 5, k = i & 31, u = row >> 2, q = row & 3;
      float sc = (q == 2) ? 2.0f * L2E : -L2E;
      float v = (u < 50) ? wih0[(q * 50 + u) * 32 + k] * sc : 0.0f;
      W[row * 32 + (k ^ ((row & 3) << 3))] = f2bf(v);
    }
  }
  {
    short* W = (short*)(img + OFF_WHH0);
    for (int i = gid; i < 208 * 64; i += nthr) {
      int row = i >> 6, k = i & 63, u = row >> 2, q = row & 3;
      float sc = (q == 2) ? 2.0f * L2E : -L2E;
      float v = (u < 50 && k < 50) ? whh0[(q * 50 + u) * 50 + k] * sc : 0.0f;
      W[row * 64 + (k ^ ((row & 7) << 3))] = f2bf(v);
    }
  }
  {
    short* W = (short*)(img + OFF_WIH1);
    for (int i = gid; i < 208 * 64; i += nthr) {
      int row = i >> 6, k = i & 63, u = row >> 2, q = row & 3;
      float sc = (q == 2) ? 2.0f * L2E : -L2E;
      float v = (u < 50 && k < 50) ? wih1[(q * 50 + u) * 50 + k] * sc : 0.0f;
      W[row * 64 + (k ^ ((row & 7) << 3))] = f2bf(v);
    }
  }
  {
    short* W = (short*)(img + OFF_WHH1);
    for (int i = gid; i < 208 * 64; i += nthr) {
      int row = i >> 6, k = i & 63, u = row >> 2, q = row & 3;
      float sc = (q == 2) ? 2.0f * L2E : -L2E;
      float v = (u < 50 && k < 50) ? whh1[(q * 50 + u) * 50 + k] * sc : 0.0f;
      W[row * 64 + (k ^ ((row & 7) << 3))] = f2bf(v);
    }
  }
  {
    float* B = (float*)(img + OFF_B0);
    for (int i = gid; i < 208; i += nthr) {
      int u = i >> 2, q = i & 3;
      float sc = (q == 2) ? 2.0f * L2E : -L2E;
      B[i] = (u < 50) ? (bih0[q * 50 + u] + bhh0[q * 50 + u]) * sc : 0.0f;
    }
  }
  {
    float* B = (float*)(img + OFF_B1);
    for (int i = gid; i < 208; i += nthr) {
      int u = i >> 2, q = i & 3;
      float sc = (q == 2) ? 2.0f * L2E : -L2E;
      B[i] = (u < 50) ? (bih1[q * 50 + u] + bhh1[q * 50 + u]) * sc : 0.0f;
    }
  }
  {
    float* F = (float*)(img + OFF_FCW);
    for (int i = gid; i < 52; i += nthr) F[i] = (i < 50) ? fcw[i] : 0.0f;
  }
}

// exp2-domain gates
__device__ __forceinline__ float gate_update(const f32x4& acc, float& cp) {
  float ei = __builtin_amdgcn_exp2f(acc[0]);
  float ef = __builtin_amdgcn_exp2f(acc[1]);
  float eo = __builtin_amdgcn_exp2f(acc[3]);
  float iv = __builtin_amdgcn_rcpf(1.0f + ei);
  float fv = __builtin_amdgcn_rcpf(1.0f + ef);
  float ov = __builtin_amdgcn_rcpf(1.0f + eo);
  float eg = __builtin_amdgcn_exp2f(fminf(acc[2], 80.0f));
  float gv = (eg - 1.0f) * __builtin_amdgcn_rcpf(eg + 1.0f);
  float c = fv * cp + iv * gv;
  cp = c;
  float Ec = __builtin_amdgcn_exp2f(c * (2.0f * L2E));
  float th = (Ec - 1.0f) * __builtin_amdgcn_rcpf(Ec + 1.0f);
  return ov * th;
}

// ================= fused 2-layer MFMA LSTM over 10 steps + FC =================
template <typename GT>
__global__ __launch_bounds__(512, 2) void k_lstm(const GT* __restrict__ gout,
    const unsigned char* __restrict__ img, const float* __restrict__ fcb_p,
    float* __restrict__ out, int N) {
  __shared__ __align__(16) unsigned char smem[160592];
  const int tid = threadIdx.x;
  {
    const uint4* s = (const uint4*)img;
    uint4* d = (uint4*)smem;
    for (int i = tid; i < IMG_BYTES / 16; i += 512) d[i] = s[i];
  }
  __syncthreads();
  const int lane = tid & 63, wid = tid >> 6;
  const int l15 = lane & 15, l4 = lane >> 4;
  const int swz7 = (l15 & 7) << 3, swz3 = (l15 & 3) << 3;
  const int node0 = blockIdx.x * 256 + wid * 32;

  const short* WIH0 = (const short*)(smem + OFF_WIH0);
  const short* WHH0 = (const short*)(smem + OFF_WHH0);
  const short* WIH1 = (const short*)(smem + OFF_WIH1);
  const short* WHH1 = (const short*)(smem + OFF_WHH1);
  const float* B0   = (const float*)(smem + OFF_B0);
  const float* B1   = (const float*)(smem + OFF_B1);
  const float* FCW  = (const float*)(smem + OFF_FCW);
  short* h0st = (short*)(smem + IMG_BYTES + wid * 8192);
  short* h1st = h0st + 2048;

  {
    uint4 z; z.x = z.y = z.z = z.w = 0u;
    uint4* p = (uint4*)h0st;
    for (int i = lane; i < 512; i += 64) p[i] = z;
  }

  // step-invariant input projection: p0r[t][v] = B0 + WIH0 . gnn  (once)
  f32x4 p0r[13][2];
  {
    short8 gfrag[2];
#pragma unroll
    for (int v = 0; v < 2; ++v) {
      int node = node0 + v * 16 + l15;
      short8 t = {0, 0, 0, 0, 0, 0, 0, 0};
      if (node < N) t = load_gfrag(gout, (size_t)node * 32 + l4 * 8);
      gfrag[v] = t;
    }
#pragma unroll
    for (int t = 0; t < 13; ++t) {
      short8 w = *(const short8*)(WIH0 + (16 * t + l15) * 32 + ((l4 * 8) ^ swz3));
      f32x4 bv = *(const f32x4*)(B0 + t * 16 + l4 * 4);
#pragma unroll
      for (int v = 0; v < 2; ++v)
        p0r[t][v] = __builtin_amdgcn_mfma_f32_16x16x32_bf16(w, gfrag[v], bv, 0, 0, 0);
    }
  }

  float c0[13][2], c1[13][2];
#pragma unroll
  for (int t = 0; t < 13; ++t) { c0[t][0]=0.f; c0[t][1]=0.f; c1[t][0]=0.f; c1[t][1]=0.f; }
  float facc[2] = {0.f, 0.f};

#pragma unroll 1
  for (int s = 0; s < 10; ++s) {
    short8 h0f[2][2], h1f[2][2];
#pragma unroll
    for (int c = 0; c < 2; ++c)
#pragma unroll
      for (int v = 0; v < 2; ++v) {
        int nl = v * 16 + l15;
        h0f[c][v] = *(const short8*)(h0st + nl * 64 + ((c * 32 + l4 * 8) ^ swz7));
        h1f[c][v] = *(const short8*)(h1st + nl * 64 + ((c * 32 + l4 * 8) ^ swz7));
      }
    // ---- layer 0 ----
#pragma unroll
    for (int t = 0; t < 13; ++t) {
      int arow = (16 * t + l15);
      short8 ah0 = *(const short8*)(WHH0 + arow * 64 + ((l4 * 8) ^ swz7));
      short8 ah1 = *(const short8*)(WHH0 + arow * 64 + ((32 + l4 * 8) ^ swz7));
#pragma unroll
      for (int v = 0; v < 2; ++v) {
        f32x4 acc = p0r[t][v];
        acc = __builtin_amdgcn_mfma_f32_16x16x32_bf16(ah0, h0f[0][v], acc, 0, 0, 0);
        acc = __builtin_amdgcn_mfma_f32_16x16x32_bf16(ah1, h0f[1][v], acc, 0, 0, 0);
        float h = gate_update(acc, c0[t][v]);
        h0st[(v * 16 + l15) * 64 + ((4 * t + l4) ^ swz7)] = f2bf(h);
      }
    }
    short8 h0nf[2][2];
#pragma unroll
    for (int c = 0; c < 2; ++c)
#pragma unroll
      for (int v = 0; v < 2; ++v) {
        int nl = v * 16 + l15;
        h0nf[c][v] = *(const short8*)(h0st + nl * 64 + ((c * 32 + l4 * 8) ^ swz7));
      }
    // ---- layer 1 ----
#pragma unroll
    for (int t = 0; t < 13; ++t) {
      f32x4 bv = *(const f32x4*)(B1 + t * 16 + l4 * 4);
      int arow = (16 * t + l15);
      short8 ai0 = *(const short8*)(WIH1 + arow * 64 + ((l4 * 8) ^ swz7));
      short8 ai1 = *(const short8*)(WIH1 + arow * 64 + ((32 + l4 * 8) ^ swz7));
      short8 ah0 = *(const short8*)(WHH1 + arow * 64 + ((l4 * 8) ^ swz7));
      short8 ah1 = *(const short8*)(WHH1 + arow * 64 + ((32 + l4 * 8) ^ swz7));
#pragma unroll
      for (int v = 0; v < 2; ++v) {
        f32x4 acc = bv;
        acc = __builtin_amdgcn_mfma_f32_16x16x32_bf16(ai0, h0nf[0][v], acc, 0, 0, 0);
        acc = __builtin_amdgcn_mfma_f32_16x16x32_bf16(ai1, h0nf[1][v], acc, 0, 0, 0);
        acc = __builtin_amdgcn_mfma_f32_16x16x32_bf16(ah0, h1f[0][v], acc, 0, 0, 0);
        acc = __builtin_amdgcn_mfma_f32_16x16x32_bf16(ah1, h1f[1][v], acc, 0, 0, 0);
        float h = gate_update(acc, c1[t][v]);
        h1st[(v * 16 + l15) * 64 + ((4 * t + l4) ^ swz7)] = f2bf(h);
        if (s == 9) {
          int u = 4 * t + l4;
          facc[v] += FCW[u] * h;
        }
      }
    }
  }
  float fcb = fcb_p[0];
#pragma unroll
  for (int v = 0; v < 2; ++v) {
    float r = facc[v];
    r += __shfl_xor(r, 16);
    r += __shfl_xor(r, 32);
    int node = node0 + v * 16 + l15;
    if (l4 == 0 && node < N) out[node] = r + fcb;
  }
}

// ================= host launcher =================
extern "C" void kernel_launch(void* const* d_in, const int* in_sizes, int n_in,
                              void* d_out, int out_size, void* d_ws, size_t ws_size,
                              hipStream_t stream) {
  const float* x    = (const float*)d_in[0];
  const float* Wg   = (const float*)d_in[1];
  const float* bg   = (const float*)d_in[2];
  const float* wih0 = (const float*)d_in[3];
  const float* whh0 = (const float*)d_in[4];
  const float* bih0 = (const float*)d_in[5];
  const float* bhh0 = (const float*)d_in[6];
  const float* wih1 = (const float*)d_in[7];
  const float* whh1 = (const float*)d_in[8];
  const float* bih1 = (const float*)d_in[9];
  const float* bhh1 = (const float*)d_in[10];
  const float* fcw  = (const float*)d_in[11];
  const float* fcb  = (const float*)d_in[12];
  const int*   edge = (const int*)d_in[13];
  int N = in_sizes[0] / 128;
  int E = in_sizes[13] / 2;

  char* ws = (char*)d_ws;
  size_t off = 0;
  auto take = [&](size_t b) {
    size_t o = off;
    off = (off + b + 255) & ~(size_t)255;
    return o;
  };
  int*   rowst = (int*)(ws + take((size_t)N * 4));
  float* dinv  = (float*)(ws + take((size_t)N * 4));
  int*   flag  = (int*)(ws + take(256));
  unsigned char* wimg = (unsigned char*)(ws + take(IMG_BYTES));

  size_t base = off;
  size_t needA = base + (((size_t)N * 128 + 255) & ~(size_t)255)
               + (((size_t)E * 4 + 255) & ~(size_t)255)
               + ((size_t)N * 128);
  size_t needB = base + (((size_t)N * 64 + 255) & ~(size_t)255)
               + (((size_t)E * 2 + 255) & ~(size_t)255)
               + ((size_t)N * 64);
  bool canU16 = (N <= 65535);

  const int NP = 8;                      // dst-range passes for k_fill
  int span = (N + NP - 1) / NP;

  hipMemsetAsync(rowst, 0, (size_t)N * 4, stream);
  k_detect<<<1, 1, 0, stream>>>(edge, flag);
  k_count<<<(E + 255) / 256, 256, 0, stream>>>(edge, E, flag, rowst);
  k_prep<<<52, 256, 0, stream>>>(wih0, whh0, wih1, whh1, bih0, bhh0, bih1, bhh1,
                                 fcw, wimg);

  if (ws_size >= needA) {
    float* gout = (float*)(ws + take((size_t)N * 128));
    int*   csr  = (int*)(ws + take((size_t)E * 4));
    float* hs   = (float*)(ws + take((size_t)N * 128));
    k_scan<<<1, 1024, 0, stream>>>(rowst, dinv, N);
    k_hs<float><<<(N + 63) / 64, 256, 0, stream>>>(x, Wg, dinv, hs, N);
    for (int p = 0; p < NP; ++p) {
      int lo = p * span, hi = min(lo + span, N);
      if (lo >= hi) break;
      k_fill<int><<<(E + 255) / 256, 256, 0, stream>>>(edge, E, flag, rowst,
                                                       csr, lo, hi);
    }
    k_gather<float, float, int><<<(N + 3) / 4, 256, 0, stream>>>(
        csr, rowst, hs, dinv, bg, gout, N);
    k_lstm<float><<<(N + 255) / 256, 512, 0, stream>>>(gout, wimg, fcb,
                                                       (float*)d_out, N);
  } else if (canU16 && ws_size >= needB) {
    __hip_bfloat16* gout = (__hip_bfloat16*)(ws + take((size_t)N * 64));
    unsigned short* csr  = (unsigned short*)(ws + take((size_t)E * 2));
    __hip_bfloat16* hs   = (__hip_bfloat16*)(ws + take((size_t)N * 64));
    k_scan<<<1, 1024, 0, stream>>>(rowst, dinv, N);
    k_hs<__hip_bfloat16><<<(N + 63) / 64, 256, 0, stream>>>(x, Wg, dinv, hs, N);
    for (int p = 0; p < NP; ++p) {
      int lo = p * span, hi = min(lo + span, N);
      if (lo >= hi) break;
      k_fill<unsigned short><<<(E + 255) / 256, 256, 0, stream>>>(
          edge, E, flag, rowst, csr, lo, hi);
    }
    k_gather<__hip_bfloat16, __hip_bfloat16, unsigned short>
        <<<(N + 3) / 4, 256, 0, stream>>>(csr, rowst, hs, dinv, bg, gout, N);
    k_lstm<__hip_bfloat16><<<(N + 255) / 256, 512, 0, stream>>>(gout, wimg, fcb,
                                                                (float*)d_out, N);
  } else {
    float* gout = (float*)(ws + take((size_t)N * 128));
    __hip_bfloat16* hs = (__hip_bfloat16*)(ws + take((size_t)N * 64));
    hipMemsetAsync(gout, 0, (size_t)N * 128, stream);
    k_dinv<<<(N + 255) / 256, 256, 0, stream>>>(rowst, dinv, N);
    k_hs<__hip_bfloat16><<<(N + 63) / 64, 256, 0, stream>>>(x, Wg, dinv, hs, N);
    int sc_blocks = (int)(((long long)E * 8 + 255) / 256);
    k_scatter<__hip_bfloat16><<<sc_blocks, 256, 0, stream>>>(edge, E, flag, hs, gout);
    k_finish<__hip_bfloat16><<<(N * 32 + 255) / 256, 256, 0, stream>>>(
        hs, dinv, bg, gout, N);
    k_lstm<float><<<(N + 255) / 256, 512, 0, stream>>>(gout, wimg, fcb,
                                                       (float*)d_out, N);
  }
}

// Round 8
// 350.475 us; speedup vs baseline: 5.0960x; 1.3552x over previous
//
#include <hip/hip_runtime.h>
#include <hip/hip_bf16.h>

typedef __attribute__((ext_vector_type(8))) short short8;
typedef __attribute__((ext_vector_type(4))) float f32x4;

#define L2E 1.442695041f
#define SCAN_B 256

__device__ __forceinline__ short f2bf(float f) {
  union { __hip_bfloat16 b; short s; } u;
  u.b = __float2bfloat16(f);
  return u.s;
}

// ---- f32/bf16 storage accessors ----
__device__ __forceinline__ float ldh(const float* p, size_t i) { return p[i]; }
__device__ __forceinline__ float ldh(const __hip_bfloat16* p, size_t i) {
  return __bfloat162float(p[i]);
}
__device__ __forceinline__ void sth(float* p, size_t i, float v) { p[i] = v; }
__device__ __forceinline__ void sth(__hip_bfloat16* p, size_t i, float v) {
  p[i] = __float2bfloat16(v);
}

__device__ __forceinline__ short8 load_gfrag(const float* g, size_t base) {
  const float4* gp = (const float4*)(g + base);
  float4 a = gp[0], b = gp[1];
  short8 t;
  t[0]=f2bf(a.x); t[1]=f2bf(a.y); t[2]=f2bf(a.z); t[3]=f2bf(a.w);
  t[4]=f2bf(b.x); t[5]=f2bf(b.y); t[6]=f2bf(b.z); t[7]=f2bf(b.w);
  return t;
}
__device__ __forceinline__ short8 load_gfrag(const __hip_bfloat16* g, size_t base) {
  return *(const short8*)(g + base);
}

// ---------------- weight image layout (bytes) ----------------
#define OFF_WIH0 0        // bf16 [208][32], swz (row&3)<<3, exp2-prescaled
#define OFF_WHH0 13312    // bf16 [208][64], swz (row&7)<<3, exp2-prescaled
#define OFF_WIH1 39936
#define OFF_WHH1 66560
#define OFF_B0   93184    // f32 [208], exp2-prescaled
#define OFF_B1   94016
#define OFF_FCW  94848    // f32 [52] (raw)
#define IMG_BYTES 95056

// ================= edge dtype autodetect =================
__global__ void k_detect(const int* __restrict__ ei, int* __restrict__ flag) {
  if (threadIdx.x == 0 && blockIdx.x == 0) {
    int odd_nz = 0, even_nz = 0;
    for (int i = 0; i < 128; ++i) {
      odd_nz |= (ei[2 * i + 1] != 0);
      even_nz |= (ei[2 * i] != 0);
    }
    *flag = (even_nz && !odd_nz) ? 1 : 0;
  }
}

// ================= GCN =================

__global__ void k_count(const int* __restrict__ ei, int E,
                        const int* __restrict__ flag, int* __restrict__ cnt) {
  int e = blockIdx.x * blockDim.x + threadIdx.x;
  if (e < E) {
    int d = (*flag) ? ei[2 * (E + e)] : ei[E + e];
    atomicAdd(&cnt[d], 1);
  }
}

__global__ void k_dinv(const int* __restrict__ cnt, float* __restrict__ dinv, int N) {
  int i = blockIdx.x * blockDim.x + threadIdx.x;
  if (i < N) dinv[i] = rsqrtf((float)cnt[i] + 1.0f);
}

// ---- grid-parallel scan, stage A: per-block sums (+dinv emission) ----
__global__ __launch_bounds__(256) void k_scanA(const int* __restrict__ cnt,
                                               float* __restrict__ dinv,
                                               int* __restrict__ bsum, int N) {
  __shared__ int red[256];
  int b = blockIdx.x, t = threadIdx.x;
  int chunk = (N + SCAN_B - 1) / SCAN_B;
  int lo = b * chunk, hi = min(lo + chunk, N);
  int s = 0;
  for (int i = lo + t; i < hi; i += 256) {
    int c = cnt[i];
    dinv[i] = rsqrtf((float)c + 1.0f);
    s += c;
  }
  red[t] = s;
  __syncthreads();
  for (int o = 128; o > 0; o >>= 1) {
    if (t < o) red[t] += red[t + o];
    __syncthreads();
  }
  if (t == 0) bsum[b] = red[0];
}

// ---- stage B: block base from bsum-scan, then tiled in-place excl scan ----
__global__ __launch_bounds__(256) void k_scanB(int* __restrict__ a,
                                               const int* __restrict__ bsum,
                                               int N) {
  __shared__ int sh[256];
  int b = blockIdx.x, t = threadIdx.x;
  int chunk = (N + SCAN_B - 1) / SCAN_B;
  int lo = b * chunk, hi = min(lo + chunk, N);
  // scan bsum[0..256) in LDS, take exclusive base for this block
  sh[t] = bsum[t];
  __syncthreads();
  for (int o = 1; o < 256; o <<= 1) {
    int u = (t >= o) ? sh[t - o] : 0;
    __syncthreads();
    sh[t] += u;
    __syncthreads();
  }
  int carry = (b == 0) ? 0 : sh[b - 1];
  __syncthreads();
  // tile-scan own chunk with carry
  for (int i0 = lo; i0 < hi; i0 += 256) {
    int i = i0 + t;
    int c = (i < hi) ? a[i] : 0;
    sh[t] = c;
    __syncthreads();
    for (int o = 1; o < 256; o <<= 1) {
      int u = (t >= o) ? sh[t - o] : 0;
      __syncthreads();
      sh[t] += u;
      __syncthreads();
    }
    if (i < hi) a[i] = carry + sh[t] - c;  // exclusive
    carry += sh[255];
    __syncthreads();
  }
}

// dst-range pass: active csr write-window stays L2-resident
template <typename CT>
__global__ void k_fill(const int* __restrict__ ei, int E,
                       const int* __restrict__ flag,
                       int* __restrict__ rowst, CT* __restrict__ csr,
                       int lo, int hi) {
  int e = blockIdx.x * blockDim.x + threadIdx.x;
  if (e < E) {
    int is64 = *flag;
    int d = is64 ? ei[2 * (E + e)] : ei[E + e];
    if (d >= lo && d < hi) {
      int s = is64 ? ei[2 * e] : ei[e];
      int p = atomicAdd(&rowst[d], 1);
      csr[p] = (CT)s;
    }
  }
}

// hs[n][g] = (x[n] @ W)[g] * dinv[n]
template <typename HT>
__global__ __launch_bounds__(256) void k_hs(const float* __restrict__ x,
                                            const float* __restrict__ Wg,
                                            const float* __restrict__ dinv,
                                            HT* __restrict__ hs, int N) {
  __shared__ __align__(16) float xt[64][132];
  __shared__ __align__(16) float Wl[128][32];
  int tid = threadIdx.x;
  int nb = blockIdx.x * 64;
  for (int i = tid; i < 4096; i += 256) Wl[i >> 5][i & 31] = Wg[i];
  const float4* xv = (const float4*)x;
  for (int i = tid; i < 2048; i += 256) {
    int r = i >> 5, c = i & 31;
    float4 v = make_float4(0.f, 0.f, 0.f, 0.f);
    if (nb + r < N) v = xv[(size_t)(nb + r) * 32 + c];
    *(float4*)&xt[r][c * 4] = v;
  }
  __syncthreads();
  int nl = tid >> 2, gq = (tid & 3) * 8;
  float a[8];
#pragma unroll
  for (int j = 0; j < 8; ++j) a[j] = 0.f;
  for (int k = 0; k < 128; ++k) {
    float xk = xt[nl][k];
#pragma unroll
    for (int j = 0; j < 8; ++j) a[j] += xk * Wl[k][gq + j];
  }
  int n = nb + nl;
  if (n < N) {
    float d = dinv[n];
#pragma unroll
    for (int j = 0; j < 8; ++j) sth(hs, (size_t)n * 32 + gq + j, a[j] * d);
  }
}

// one wave per node; index-broadcast gather: all hs loads independent
template <typename HT, typename GT, typename CT>
__global__ void k_gather(const CT* __restrict__ csr, const int* __restrict__ rowst,
                         const HT* __restrict__ hs, const float* __restrict__ dinv,
                         const float* __restrict__ bg, GT* __restrict__ gout,
                         int N) {
  int w = (blockIdx.x * blockDim.x + threadIdx.x) >> 6;
  if (w >= N) return;
  int l = threadIdx.x & 63;
  int g = l & 31, j = l >> 5;
  int end = rowst[w];
  int start = (w == 0) ? 0 : rowst[w - 1];
  int deg = end - start;
  int dmax = min(deg, 64);
  int idx = (l < deg) ? (int)csr[start + l] : 0;
  float acc = 0.0f;
#pragma unroll 1
  for (int base = 0; base < 64; base += 16) {
    if (base >= dmax) break;
#pragma unroll
    for (int i = 0; i < 8; ++i) {
      int e = base + 2 * i + j;
      int src = __shfl(idx, e);
      float v = ldh(hs, (size_t)src * 32 + g);
      acc += (e < dmax) ? v : 0.0f;
    }
  }
  for (int k = start + 64 + j; k < end; k += 2)
    acc += ldh(hs, (size_t)csr[k] * 32 + g);
  acc += __shfl_xor(acc, 32);
  if (j == 0) {
    float v = (acc + ldh(hs, (size_t)w * 32 + g)) * dinv[w] + bg[g];
    sth(gout, (size_t)w * 32 + g, v);
  }
}

// ---- scatter fallback ----
template <typename HT>
__global__ void k_scatter(const int* __restrict__ ei, int E,
                          const int* __restrict__ flag,
                          const HT* __restrict__ hs, float* __restrict__ gout) {
  long long gid = (long long)blockIdx.x * blockDim.x + threadIdx.x;
  int e = (int)(gid >> 3), part = (int)(gid & 7);
  if (e >= E) return;
  int is64 = *flag;
  int s = is64 ? ei[2 * e] : ei[e];
  int d = is64 ? ei[2 * (E + e)] : ei[E + e];
  int b = part * 4;
  float* gp = gout + (size_t)d * 32 + b;
  size_t hp = (size_t)s * 32 + b;
  atomicAdd(gp + 0, ldh(hs, hp + 0));
  atomicAdd(gp + 1, ldh(hs, hp + 1));
  atomicAdd(gp + 2, ldh(hs, hp + 2));
  atomicAdd(gp + 3, ldh(hs, hp + 3));
}
template <typename HT>
__global__ void k_finish(const HT* __restrict__ hs, const float* __restrict__ dinv,
                         const float* __restrict__ bg, float* __restrict__ gout,
                         int N) {
  int gid = blockIdx.x * blockDim.x + threadIdx.x;
  if (gid < N * 32) {
    int n = gid >> 5, g = gid & 31;
    gout[gid] = (gout[gid] + ldh(hs, (size_t)gid)) * dinv[n] + bg[g];
  }
}

// ================= weight image prep (exp2-prescaled) =================
__global__ void k_prep(const float* __restrict__ wih0, const float* __restrict__ whh0,
                       const float* __restrict__ wih1, const float* __restrict__ whh1,
                       const float* __restrict__ bih0, const float* __restrict__ bhh0,
                       const float* __restrict__ bih1, const float* __restrict__ bhh1,
                       const float* __restrict__ fcw, unsigned char* __restrict__ img) {
  int gid = blockIdx.x * blockDim.x + threadIdx.x;
  int nthr = gridDim.x * blockDim.x;
  {
    short* W = (short*)(img + OFF_WIH0);
    for (int i = gid; i < 208 * 32; i += nthr) {
      int row = i >> 5, k = i & 31, u = row >> 2, q = row & 3;
      float sc = (q == 2) ? 2.0f * L2E : -L2E;
      float v = (u < 50) ? wih0[(q * 50 + u) * 32 + k] * sc : 0.0f;
      W[row * 32 + (k ^ ((row & 3) << 3))] = f2bf(v);
    }
  }
  {
    short* W = (short*)(img + OFF_WHH0);
    for (int i = gid; i < 208 * 64; i += nthr) {
      int row = i >> 6, k = i & 63, u = row >> 2, q = row & 3;
      float sc = (q == 2) ? 2.0f * L2E : -L2E;
      float v = (u < 50 && k < 50) ? whh0[(q * 50 + u) * 50 + k] * sc : 0.0f;
      W[row * 64 + (k ^ ((row & 7) << 3))] = f2bf(v);
    }
  }
  {
    short* W = (short*)(img + OFF_WIH1);
    for (int i = gid; i < 208 * 64; i += nthr) {
      int row = i >> 6, k = i & 63, u = row >> 2, q = row & 3;
      float sc = (q == 2) ? 2.0f * L2E : -L2E;
      float v = (u < 50 && k < 50) ? wih1[(q * 50 + u) * 50 + k] * sc : 0.0f;
      W[row * 64 + (k ^ ((row & 7) << 3))] = f2bf(v);
    }
  }
  {
    short* W = (short*)(img + OFF_WHH1);
    for (int i = gid; i < 208 * 64; i += nthr) {
      int row = i >> 6, k = i & 63, u = row >> 2, q = row & 3;
      float sc = (q == 2) ? 2.0f * L2E : -L2E;
      float v = (u < 50 && k < 50) ? whh1[(q * 50 + u) * 50 + k] * sc : 0.0f;
      W[row * 64 + (k ^ ((row & 7) << 3))] = f2bf(v);
    }
  }
  {
    float* B = (float*)(img + OFF_B0);
    for (int i = gid; i < 208; i += nthr) {
      int u = i >> 2, q = i & 3;
      float sc = (q == 2) ? 2.0f * L2E : -L2E;
      B[i] = (u < 50) ? (bih0[q * 50 + u] + bhh0[q * 50 + u]) * sc : 0.0f;
    }
  }
  {
    float* B = (float*)(img + OFF_B1);
    for (int i = gid; i < 208; i += nthr) {
      int u = i >> 2, q = i & 3;
      float sc = (q == 2) ? 2.0f * L2E : -L2E;
      B[i] = (u < 50) ? (bih1[q * 50 + u] + bhh1[q * 50 + u]) * sc : 0.0f;
    }
  }
  {
    float* F = (float*)(img + OFF_FCW);
    for (int i = gid; i < 52; i += nthr) F[i] = (i < 50) ? fcw[i] : 0.0f;
  }
}

// exp2-domain gates
__device__ __forceinline__ float gate_update(const f32x4& acc, float& cp) {
  float ei = __builtin_amdgcn_exp2f(acc[0]);
  float ef = __builtin_amdgcn_exp2f(acc[1]);
  float eo = __builtin_amdgcn_exp2f(acc[3]);
  float iv = __builtin_amdgcn_rcpf(1.0f + ei);
  float fv = __builtin_amdgcn_rcpf(1.0f + ef);
  float ov = __builtin_amdgcn_rcpf(1.0f + eo);
  float eg = __builtin_amdgcn_exp2f(fminf(acc[2], 80.0f));
  float gv = (eg - 1.0f) * __builtin_amdgcn_rcpf(eg + 1.0f);
  float c = fv * cp + iv * gv;
  cp = c;
  float Ec = __builtin_amdgcn_exp2f(c * (2.0f * L2E));
  float th = (Ec - 1.0f) * __builtin_amdgcn_rcpf(Ec + 1.0f);
  return ov * th;
}

// ================= fused 2-layer MFMA LSTM over 10 steps + FC =================
template <typename GT>
__global__ __launch_bounds__(512, 2) void k_lstm(const GT* __restrict__ gout,
    const unsigned char* __restrict__ img, const float* __restrict__ fcb_p,
    float* __restrict__ out, int N) {
  __shared__ __align__(16) unsigned char smem[160592];
  const int tid = threadIdx.x;
  {
    const uint4* s = (const uint4*)img;
    uint4* d = (uint4*)smem;
    for (int i = tid; i < IMG_BYTES / 16; i += 512) d[i] = s[i];
  }
  __syncthreads();
  const int lane = tid & 63, wid = tid >> 6;
  const int l15 = lane & 15, l4 = lane >> 4;
  const int swz7 = (l15 & 7) << 3, swz3 = (l15 & 3) << 3;
  const int node0 = blockIdx.x * 256 + wid * 32;

  const short* WIH0 = (const short*)(smem + OFF_WIH0);
  const short* WHH0 = (const short*)(smem + OFF_WHH0);
  const short* WIH1 = (const short*)(smem + OFF_WIH1);
  const short* WHH1 = (const short*)(smem + OFF_WHH1);
  const float* B0   = (const float*)(smem + OFF_B0);
  const float* B1   = (const float*)(smem + OFF_B1);
  const float* FCW  = (const float*)(smem + OFF_FCW);
  short* h0st = (short*)(smem + IMG_BYTES + wid * 8192);
  short* h1st = h0st + 2048;

  {
    uint4 z; z.x = z.y = z.z = z.w = 0u;
    uint4* p = (uint4*)h0st;
    for (int i = lane; i < 512; i += 64) p[i] = z;
  }

  // step-invariant input projection: p0r[t][v] = B0 + WIH0 . gnn  (once)
  f32x4 p0r[13][2];
  {
    short8 gfrag[2];
#pragma unroll
    for (int v = 0; v < 2; ++v) {
      int node = node0 + v * 16 + l15;
      short8 t = {0, 0, 0, 0, 0, 0, 0, 0};
      if (node < N) t = load_gfrag(gout, (size_t)node * 32 + l4 * 8);
      gfrag[v] = t;
    }
#pragma unroll
    for (int t = 0; t < 13; ++t) {
      short8 w = *(const short8*)(WIH0 + (16 * t + l15) * 32 + ((l4 * 8) ^ swz3));
      f32x4 bv = *(const f32x4*)(B0 + t * 16 + l4 * 4);
#pragma unroll
      for (int v = 0; v < 2; ++v)
        p0r[t][v] = __builtin_amdgcn_mfma_f32_16x16x32_bf16(w, gfrag[v], bv, 0, 0, 0);
    }
  }

  float c0[13][2], c1[13][2];
#pragma unroll
  for (int t = 0; t < 13; ++t) { c0[t][0]=0.f; c0[t][1]=0.f; c1[t][0]=0.f; c1[t][1]=0.f; }
  float facc[2] = {0.f, 0.f};

#pragma unroll 1
  for (int s = 0; s < 10; ++s) {
    short8 h0f[2][2], h1f[2][2];
#pragma unroll
    for (int c = 0; c < 2; ++c)
#pragma unroll
      for (int v = 0; v < 2; ++v) {
        int nl = v * 16 + l15;
        h0f[c][v] = *(const short8*)(h0st + nl * 64 + ((c * 32 + l4 * 8) ^ swz7));
        h1f[c][v] = *(const short8*)(h1st + nl * 64 + ((c * 32 + l4 * 8) ^ swz7));
      }
    // ---- layer 0 ----
#pragma unroll
    for (int t = 0; t < 13; ++t) {
      int arow = (16 * t + l15);
      short8 ah0 = *(const short8*)(WHH0 + arow * 64 + ((l4 * 8) ^ swz7));
      short8 ah1 = *(const short8*)(WHH0 + arow * 64 + ((32 + l4 * 8) ^ swz7));
#pragma unroll
      for (int v = 0; v < 2; ++v) {
        f32x4 acc = p0r[t][v];
        acc = __builtin_amdgcn_mfma_f32_16x16x32_bf16(ah0, h0f[0][v], acc, 0, 0, 0);
        acc = __builtin_amdgcn_mfma_f32_16x16x32_bf16(ah1, h0f[1][v], acc, 0, 0, 0);
        float h = gate_update(acc, c0[t][v]);
        h0st[(v * 16 + l15) * 64 + ((4 * t + l4) ^ swz7)] = f2bf(h);
      }
    }
    short8 h0nf[2][2];
#pragma unroll
    for (int c = 0; c < 2; ++c)
#pragma unroll
      for (int v = 0; v < 2; ++v) {
        int nl = v * 16 + l15;
        h0nf[c][v] = *(const short8*)(h0st + nl * 64 + ((c * 32 + l4 * 8) ^ swz7));
      }
    // ---- layer 1 ----
#pragma unroll
    for (int t = 0; t < 13; ++t) {
      f32x4 bv = *(const f32x4*)(B1 + t * 16 + l4 * 4);
      int arow = (16 * t + l15);
      short8 ai0 = *(const short8*)(WIH1 + arow * 64 + ((l4 * 8) ^ swz7));
      short8 ai1 = *(const short8*)(WIH1 + arow * 64 + ((32 + l4 * 8) ^ swz7));
      short8 ah0 = *(const short8*)(WHH1 + arow * 64 + ((l4 * 8) ^ swz7));
      short8 ah1 = *(const short8*)(WHH1 + arow * 64 + ((32 + l4 * 8) ^ swz7));
#pragma unroll
      for (int v = 0; v < 2; ++v) {
        f32x4 acc = bv;
        acc = __builtin_amdgcn_mfma_f32_16x16x32_bf16(ai0, h0nf[0][v], acc, 0, 0, 0);
        acc = __builtin_amdgcn_mfma_f32_16x16x32_bf16(ai1, h0nf[1][v], acc, 0, 0, 0);
        acc = __builtin_amdgcn_mfma_f32_16x16x32_bf16(ah0, h1f[0][v], acc, 0, 0, 0);
        acc = __builtin_amdgcn_mfma_f32_16x16x32_bf16(ah1, h1f[1][v], acc, 0, 0, 0);
        float h = gate_update(acc, c1[t][v]);
        h1st[(v * 16 + l15) * 64 + ((4 * t + l4) ^ swz7)] = f2bf(h);
        if (s == 9) {
          int u = 4 * t + l4;
          facc[v] += FCW[u] * h;
        }
      }
    }
  }
  float fcb = fcb_p[0];
#pragma unroll
  for (int v = 0; v < 2; ++v) {
    float r = facc[v];
    r += __shfl_xor(r, 16);
    r += __shfl_xor(r, 32);
    int node = node0 + v * 16 + l15;
    if (l4 == 0 && node < N) out[node] = r + fcb;
  }
}

// ================= host launcher =================
extern "C" void kernel_launch(void* const* d_in, const int* in_sizes, int n_in,
                              void* d_out, int out_size, void* d_ws, size_t ws_size,
                              hipStream_t stream) {
  const float* x    = (const float*)d_in[0];
  const float* Wg   = (const float*)d_in[1];
  const float* bg   = (const float*)d_in[2];
  const float* wih0 = (const float*)d_in[3];
  const float* whh0 = (const float*)d_in[4];
  const float* bih0 = (const float*)d_in[5];
  const float* bhh0 = (const float*)d_in[6];
  const float* wih1 = (const float*)d_in[7];
  const float* whh1 = (const float*)d_in[8];
  const float* bih1 = (const float*)d_in[9];
  const float* bhh1 = (const float*)d_in[10];
  const float* fcw  = (const float*)d_in[11];
  const float* fcb  = (const float*)d_in[12];
  const int*   edge = (const int*)d_in[13];
  int N = in_sizes[0] / 128;
  int E = in_sizes[13] / 2;

  char* ws = (char*)d_ws;
  size_t off = 0;
  auto take = [&](size_t b) {
    size_t o = off;
    off = (off + b + 255) & ~(size_t)255;
    return o;
  };
  int*   rowst = (int*)(ws + take((size_t)N * 4));
  float* dinv  = (float*)(ws + take((size_t)N * 4));
  int*   flag  = (int*)(ws + take(256));
  int*   bsum  = (int*)(ws + take(SCAN_B * 4));
  unsigned char* wimg = (unsigned char*)(ws + take(IMG_BYTES));

  size_t base = off;
  size_t needA = base + (((size_t)N * 128 + 255) & ~(size_t)255)
               + (((size_t)E * 4 + 255) & ~(size_t)255)
               + ((size_t)N * 128);
  size_t needB = base + (((size_t)N * 64 + 255) & ~(size_t)255)
               + (((size_t)E * 2 + 255) & ~(size_t)255)
               + ((size_t)N * 64);
  bool canU16 = (N <= 65535);

  const int NP = 8;                      // dst-range passes for k_fill
  int span = (N + NP - 1) / NP;

  hipMemsetAsync(rowst, 0, (size_t)N * 4, stream);
  k_detect<<<1, 1, 0, stream>>>(edge, flag);
  k_count<<<(E + 255) / 256, 256, 0, stream>>>(edge, E, flag, rowst);
  k_prep<<<52, 256, 0, stream>>>(wih0, whh0, wih1, whh1, bih0, bhh0, bih1, bhh1,
                                 fcw, wimg);

  if (ws_size >= needA) {
    float* gout = (float*)(ws + take((size_t)N * 128));
    int*   csr  = (int*)(ws + take((size_t)E * 4));
    float* hs   = (float*)(ws + take((size_t)N * 128));
    k_scanA<<<SCAN_B, 256, 0, stream>>>(rowst, dinv, bsum, N);
    k_scanB<<<SCAN_B, 256, 0, stream>>>(rowst, bsum, N);
    k_hs<float><<<(N + 63) / 64, 256, 0, stream>>>(x, Wg, dinv, hs, N);
    for (int p = 0; p < NP; ++p) {
      int lo = p * span, hi = min(lo + span, N);
      if (lo >= hi) break;
      k_fill<int><<<(E + 255) / 256, 256, 0, stream>>>(edge, E, flag, rowst,
                                                       csr, lo, hi);
    }
    k_gather<float, float, int><<<(N + 3) / 4, 256, 0, stream>>>(
        csr, rowst, hs, dinv, bg, gout, N);
    k_lstm<float><<<(N + 255) / 256, 512, 0, stream>>>(gout, wimg, fcb,
                                                       (float*)d_out, N);
  } else if (canU16 && ws_size >= needB) {
    __hip_bfloat16* gout = (__hip_bfloat16*)(ws + take((size_t)N * 64));
    unsigned short* csr  = (unsigned short*)(ws + take((size_t)E * 2));
    __hip_bfloat16* hs   = (__hip_bfloat16*)(ws + take((size_t)N * 64));
    k_scanA<<<SCAN_B, 256, 0, stream>>>(rowst, dinv, bsum, N);
    k_scanB<<<SCAN_B, 256, 0, stream>>>(rowst, bsum, N);
    k_hs<__hip_bfloat16><<<(N + 63) / 64, 256, 0, stream>>>(x, Wg, dinv, hs, N);
    for (int p = 0; p < NP; ++p) {
      int lo = p * span, hi = min(lo + span, N);
      if (lo >= hi) break;
      k_fill<unsigned short><<<(E + 255) / 256, 256, 0, stream>>>(
          edge, E, flag, rowst, csr, lo, hi);
    }
    k_gather<__hip_bfloat16, __hip_bfloat16, unsigned short>
        <<<(N + 3) / 4, 256, 0, stream>>>(csr, rowst, hs, dinv, bg, gout, N);
    k_lstm<__hip_bfloat16><<<(N + 255) / 256, 512, 0, stream>>>(gout, wimg, fcb,
                                                                (float*)d_out, N);
  } else {
    float* gout = (float*)(ws + take((size_t)N * 128));
    __hip_bfloat16* hs = (__hip_bfloat16*)(ws + take((size_t)N * 64));
    hipMemsetAsync(gout, 0, (size_t)N * 128, stream);
    k_dinv<<<(N + 255) / 256, 256, 0, stream>>>(rowst, dinv, N);
    k_hs<__hip_bfloat16><<<(N + 63) / 64, 256, 0, stream>>>(x, Wg, dinv, hs, N);
    int sc_blocks = (int)(((long long)E * 8 + 255) / 256);
    k_scatter<__hip_bfloat16><<<sc_blocks, 256, 0, stream>>>(edge, E, flag, hs, gout);
    k_finish<__hip_bfloat16><<<(N * 32 + 255) / 256, 256, 0, stream>>>(
        hs, dinv, bg, gout, N);
    k_lstm<float><<<(N + 255) / 256, 512, 0, stream>>>(gout, wimg, fcb,
                                                       (float*)d_out, N);
  }
}